// Round 13
// baseline (699.502 us; speedup 1.0000x reference)
//
#include <hip/hip_runtime.h>
#include <math.h>

typedef _Float16 half_t;
typedef __attribute__((ext_vector_type(8))) _Float16 f16x8;
typedef __attribute__((ext_vector_type(4))) _Float16 f16x4;
typedef __attribute__((ext_vector_type(4))) float f32x4;

#define LEAKY(v, s) ((v) >= 0.f ? (v) : (s) * (v))

__device__ __forceinline__ float sig_(float x) { return 1.f / (1.f + expf(-x)); }
__device__ __forceinline__ half_t f2h(float f) { return (half_t)f; }

#define GLD(gp, lp)                                              \
  __builtin_amdgcn_global_load_lds(                              \
      (const __attribute__((address_space(1))) void*)(gp),       \
      (__attribute__((address_space(3))) void*)(lp), 16, 0, 0)

#define PHASE_WAIT(N)                                            \
  asm volatile("s_waitcnt vmcnt(" #N ")" ::: "memory");          \
  __builtin_amdgcn_s_barrier();                                  \
  __builtin_amdgcn_sched_barrier(0)

// ---------------- merged prep: elementwise segments + LDS-bounce transposes ----
#define R0 2048LL      // bg0
#define R1 4096LL      // bg1
#define R2 135168LL    // c zero (131072 f32)
#define R3 266240LL    // h zero (131072 u32)
#define R4 266688LL    // cnt zero (448 u32)
#define R5 5284288LL   // pad_x (5017600)
#define R6 5310912LL   // w1r (26624)
#define R7 6359488LL   // wih0h (1048576)
#define R8 6621632LL   // fw1h (262144)
#define R9 7670208LL   // wcat0 (1048576)
#define R10 9767360LL  // wcat1 end
#define ELEM_BLOCKS 38154

__global__ __launch_bounds__(256) void prep_main(
    const float* __restrict__ x, const float* __restrict__ w1,
    const float* __restrict__ w2, const float* __restrict__ w3,
    const float* __restrict__ w4, const float* __restrict__ w5,
    const float* __restrict__ wih0, const float* __restrict__ whh0,
    const float* __restrict__ bih0, const float* __restrict__ bhh0,
    const float* __restrict__ wih1, const float* __restrict__ whh1,
    const float* __restrict__ bih1, const float* __restrict__ bhh1,
    const float* __restrict__ fw1,
    float* __restrict__ bg0, float* __restrict__ bg1,
    float* __restrict__ czero, unsigned* __restrict__ hzero,
    unsigned* __restrict__ cntz,
    half_t* __restrict__ xpad, half_t* __restrict__ w1r,
    half_t* __restrict__ w2r, half_t* __restrict__ w3r,
    half_t* __restrict__ w4r, half_t* __restrict__ w5r,
    half_t* __restrict__ wih0h, half_t* __restrict__ fw1h,
    half_t* __restrict__ wcat0h, half_t* __restrict__ wcat1h) {
  __shared__ float T[12800];
  const int tid = threadIdx.x;
  if (blockIdx.x >= ELEM_BLOCKS) {
    // ---- LDS-bounce weight transpose path ----
    int bid = blockIdx.x - ELEM_BLOCKS;
    const float* W;
    half_t* D;
    int co, Cin, TAP, lg2;
    if (bid < 128) {
      W = w2; D = w2r; co = bid; Cin = 64; TAP = 49; lg2 = 6;
    } else if (bid < 384) {
      W = w3; D = w3r; co = bid - 128; Cin = 128; TAP = 25; lg2 = 7;
    } else if (bid < 896) {
      W = w4; D = w4r; co = bid - 384; Cin = 256; TAP = 25; lg2 = 8;
    } else {
      W = w5; D = w5r; co = bid - 896; Cin = 512; TAP = 25; lg2 = 9;
    }
    int n = Cin * TAP;
    const float* src = W + (size_t)co * n;
    for (int i = tid; i < n; i += 256) T[i] = src[i];
    __syncthreads();
    half_t* dst = D + (size_t)co * n;
    for (int j = tid; j < n; j += 256) {
      int ci = j & (Cin - 1);
      int tap = j >> lg2;
      dst[j] = f2h(T[ci * TAP + tap]);
    }
    return;
  }
  long long i = (long long)blockIdx.x * 256 + tid;
  if (i < R0) {
    bg0[i] = bih0[i] + bhh0[i];
  } else if (i < R1) {
    long long j = i - R0;
    bg1[j] = bih1[j] + bhh1[j];
  } else if (i < R2) {
    czero[i - R1] = 0.f;
  } else if (i < R3) {
    hzero[i - R2] = 0u;
  } else if (i < R4) {
    cntz[i - R3] = 0u;
  } else if (i < R5) {
    long long j = i - R4;
    int c = j & 7;
    long long t = j >> 3;
    int iw = t % 70; t /= 70;
    int ih = t % 70;
    int n = t / 70;
    float v = 0.f;
    if (c < 3 && ih >= 3 && ih < 67 && iw >= 3 && iw < 67)
      v = x[((n * 3 + c) * 64 + (ih - 3)) * 64 + (iw - 3)];
    xpad[j] = f2h(v);
  } else if (i < R6) {
    int j = (int)(i - R5);
    int kg = j % 416, co = j / 416;
    int ci = kg & 7, tap = kg >> 3;
    float v = 0.f;
    if (tap < 49 && ci < 3) {
      int kh = tap / 7, kw = tap % 7;
      v = w1[((co * 3 + ci) * 7 + kh) * 7 + kw];
    }
    w1r[j] = f2h(v);
  } else if (i < R7) {
    int j = (int)(i - R6);
    wih0h[j] = f2h(wih0[j]);
  } else if (i < R8) {
    int j = (int)(i - R7);
    fw1h[j] = f2h(fw1[j]);
  } else if (i < R9) {
    int j = (int)(i - R8);
    int r = j >> 9, k = j & 511;
    int u = r >> 2, g = r & 3;
    wcat0h[j] = f2h(whh0[(g * 512 + u) * 512 + k]);
  } else if (i < R10) {
    int j = (int)(i - R9);
    int r = j >> 10, k = j & 1023;
    int u = r >> 2, g = r & 3;
    int row = g * 512 + u;
    wcat1h[j] = f2h(k < 512 ? wih1[row * 512 + k] : whh1[row * 512 + (k - 512)]);
  }
}

// ---------------- 64x64 fp16 MFMA conv / GEMM ----------------
// OUTMODE: 0 fp16+bias+leaky; 1 f32+bias+leaky; 4 f32 partial + in-kernel fixup.
template <int KW, int S, int LOG2CIN, int OUTMODE>
__global__ __launch_bounds__(256) void conv_mfma(
    const half_t* __restrict__ xin, const half_t* __restrict__ wr,
    const float* __restrict__ bias, void* __restrict__ outp,
    int Hin, int Win, int Hout, int Wout, int Cout, int K, int ktiles, float slope,
    long long zstride, void* pbuf, unsigned* cnt, int Z) {
  constexpr int CIN = 1 << LOG2CIN;
  __shared__ half_t lds[4][4096];
  __shared__ unsigned lastf;
  const int tid = threadIdx.x;
  const int lane = tid & 63, wid = tid >> 6;
  const int sRow = tid >> 2, sCh = tid & 3;
  const int sSwz = sCh ^ ((sRow ^ (sRow >> 2)) & 3);
  const int kt0 = blockIdx.z * ktiles;
  const half_t* gArow = wr + (size_t)(blockIdx.y * 64 + sRow) * K + sSwz * 8;
  int p = blockIdx.x * 64 + sRow;
  int hw = Hout * Wout;
  int n = p / hw;
  int rem = p - n * hw;
  int oh = rem / Wout;
  int ow = rem - oh * Wout;
  const half_t* xb = xin + ((size_t)(n * Hin + oh * S) * Win + ow * S) * CIN;
  const int fr = lane & 15, fc = lane >> 4;
  const int r0 = (wid & 1) * 32, c0 = (wid >> 1) * 32;
  const int sw = (fc ^ ((fr ^ (fr >> 2)) & 3)) * 8;
  const int ia0 = (r0 + fr) * 32 + sw;
  const int ia1 = (r0 + 16 + fr) * 32 + sw;
  const int ib0 = 2048 + (c0 + fr) * 32 + sw;
  const int ib1 = 2048 + (c0 + 16 + fr) * 32 + sw;

  auto stage = [&](int t, int buf) {
    GLD(gArow + (size_t)(kt0 + t) * 32, &lds[buf][wid * 512]);
    int kg = (kt0 + t) * 32 + sSwz * 8;
    int ci = kg & (CIN - 1);
    int tap = kg >> LOG2CIN;
    int kh = tap / KW, kw = tap - kh * KW;
    GLD(xb + (kh * Win + kw) * CIN + ci, &lds[buf][2048 + wid * 512]);
  };

  f32x4 acc00 = {0.f, 0.f, 0.f, 0.f};
  f32x4 acc01 = acc00, acc10 = acc00, acc11 = acc00;

  auto compute = [&](int buf) {
    const half_t* L = &lds[buf][0];
    f16x8 a0 = *(const f16x8*)&L[ia0];
    f16x8 a1 = *(const f16x8*)&L[ia1];
    f16x8 b0 = *(const f16x8*)&L[ib0];
    f16x8 b1 = *(const f16x8*)&L[ib1];
    acc00 = __builtin_amdgcn_mfma_f32_16x16x32_f16(a0, b0, acc00, 0, 0, 0);
    acc01 = __builtin_amdgcn_mfma_f32_16x16x32_f16(a0, b1, acc01, 0, 0, 0);
    acc10 = __builtin_amdgcn_mfma_f32_16x16x32_f16(a1, b0, acc10, 0, 0, 0);
    acc11 = __builtin_amdgcn_mfma_f32_16x16x32_f16(a1, b1, acc11, 0, 0, 0);
  };

  stage(0, 0);
  stage(1, 1);
  stage(2, 2);
  int t = 0;
  for (; t < ktiles - 3; ++t) {
    PHASE_WAIT(4);
    stage(t + 3, (t + 3) & 3);
    compute(t & 3);
  }
  PHASE_WAIT(4);
  compute(t & 3);
  ++t;
  PHASE_WAIT(2);
  compute(t & 3);
  ++t;
  PHASE_WAIT(0);
  compute(t & 3);

#pragma unroll
  for (int am = 0; am < 2; ++am) {
#pragma unroll
    for (int bn = 0; bn < 2; ++bn) {
      f32x4 a = am == 0 ? (bn == 0 ? acc00 : acc01) : (bn == 0 ? acc10 : acc11);
      int co = blockIdx.y * 64 + r0 + am * 16 + fc * 4;
      int px = blockIdx.x * 64 + c0 + bn * 16 + fr;
      size_t o = (size_t)px * Cout + co;
      if (OUTMODE == 4) {
        float* myp = (float*)pbuf + (size_t)blockIdx.z * zstride;
        *(f32x4*)&myp[o] = a;
      } else {
        f32x4 bb = *(const f32x4*)&bias[co];
        f32x4 v;
#pragma unroll
        for (int j = 0; j < 4; ++j) {
          float tt = a[j] + bb[j];
          v[j] = LEAKY(tt, slope);
        }
        if (OUTMODE == 1) {
          *(f32x4*)&((float*)outp)[o] = v;
        } else {
          f16x4 hv;
#pragma unroll
          for (int j = 0; j < 4; ++j) hv[j] = f2h(v[j]);
          *(f16x4*)&((half_t*)outp)[o] = hv;
        }
      }
    }
  }

  if (OUTMODE == 4) {
    __threadfence();
    if (tid == 0) {
      unsigned c = __hip_atomic_fetch_add(cnt + (blockIdx.x * gridDim.y + blockIdx.y),
                                          1u, __ATOMIC_ACQ_REL, __HIP_MEMORY_SCOPE_AGENT);
      lastf = (c == (unsigned)(Z - 1)) ? 1u : 0u;
    }
    __syncthreads();
    if (!lastf) return;
    half_t* outh = (half_t*)outp;
#pragma unroll
    for (int am = 0; am < 2; ++am) {
#pragma unroll
      for (int bn = 0; bn < 2; ++bn) {
        int co = blockIdx.y * 64 + r0 + am * 16 + fc * 4;
        int px = blockIdx.x * 64 + c0 + bn * 16 + fr;
        size_t o = (size_t)px * Cout + co;
        f32x4 s = *(const f32x4*)&bias[co];
        for (int z = 0; z < Z; ++z) {
          f32x4 pv = *(const f32x4*)&((float*)pbuf)[(size_t)z * zstride + o];
#pragma unroll
          for (int j = 0; j < 4; ++j) s[j] += pv[j];
        }
        f16x4 hv;
#pragma unroll
        for (int j = 0; j < 4; ++j) hv[j] = f2h(LEAKY(s[j], slope));
        *(f16x4*)&outh[o] = hv;
      }
    }
  }
}

// ---------------- 128x128 fp16 MFMA conv, XCD-swizzled 1D grid ----------------
// OUTMODE: 0 fp16+bias+leaky; 4 fp16 partial + in-kernel fixup (split-K).
template <int KW, int S, int LOG2CIN, int OUTMODE>
__global__ __launch_bounds__(256) void conv_mfma128(
    const half_t* __restrict__ xin, const half_t* __restrict__ wr,
    const float* __restrict__ bias, void* __restrict__ outp,
    int Hin, int Win, int Hout, int Wout, int Cout, int K, int ktiles, float slope,
    long long zstride, int Y, int G, void* pbuf, unsigned* cnt, int Z) {
  constexpr int CIN = 1 << LOG2CIN;
  __shared__ half_t lds[4][8192];
  __shared__ unsigned lastf;
  const int L = blockIdx.x;
  const int bx = L / G;
  const int g = L % G;
  const int by = g % Y;
  const int bz = g / Y;
  const int tid = threadIdx.x;
  const int lane = tid & 63, wid = tid >> 6;
  const int sRow = tid >> 2, sCh = tid & 3;
  const int sSwz = sCh ^ ((sRow ^ (sRow >> 2)) & 3);
  const int kt0 = bz * ktiles;
  const half_t* gA0 = wr + (size_t)(by * 128 + sRow) * K + sSwz * 8;
  const half_t* gA1 = wr + (size_t)(by * 128 + 64 + sRow) * K + sSwz * 8;
  int hw = Hout * Wout;
  int p0 = bx * 128 + sRow;
  int n0 = p0 / hw, r0p = p0 - n0 * hw, oh0 = r0p / Wout, ow0 = r0p - oh0 * Wout;
  const half_t* xb0 = xin + ((size_t)(n0 * Hin + oh0 * S) * Win + ow0 * S) * CIN;
  int p1 = p0 + 64;
  int n1 = p1 / hw, r1p = p1 - n1 * hw, oh1 = r1p / Wout, ow1 = r1p - oh1 * Wout;
  const half_t* xb1 = xin + ((size_t)(n1 * Hin + oh1 * S) * Win + ow1 * S) * CIN;

  const int fr = lane & 15, fc = lane >> 4;
  const int wr_ = wid & 1, wc_ = wid >> 1;
  const int sw = (fc ^ ((fr ^ (fr >> 2)) & 3)) * 8;
  const int iaB = (wr_ * 64 + fr) * 32 + sw;
  const int ibB = 4096 + (wc_ * 64 + fr) * 32 + sw;

  auto stage = [&](int t, int buf) {
    half_t* LB = &lds[buf][0];
    GLD(gA0 + (size_t)(kt0 + t) * 32, LB + wid * 512);
    GLD(gA1 + (size_t)(kt0 + t) * 32, LB + 2048 + wid * 512);
    int kg = (kt0 + t) * 32 + sSwz * 8;
    int ci = kg & (CIN - 1);
    int tap = kg >> LOG2CIN;
    int kh = tap / KW, kw = tap - kh * KW;
    int xoff = (kh * Win + kw) * CIN + ci;
    GLD(xb0 + xoff, LB + 4096 + wid * 512);
    GLD(xb1 + xoff, LB + 6144 + wid * 512);
  };

  f32x4 acc[4][4];
#pragma unroll
  for (int i = 0; i < 4; ++i)
#pragma unroll
    for (int j = 0; j < 4; ++j) acc[i][j] = (f32x4){0.f, 0.f, 0.f, 0.f};

  auto compute = [&](int buf) {
    const half_t* L2 = &lds[buf][0];
    f16x8 a[4], b[4];
#pragma unroll
    for (int fi = 0; fi < 4; ++fi) a[fi] = *(const f16x8*)&L2[iaB + fi * 512];
#pragma unroll
    for (int fj = 0; fj < 4; ++fj) b[fj] = *(const f16x8*)&L2[ibB + fj * 512];
#pragma unroll
    for (int fi = 0; fi < 4; ++fi)
#pragma unroll
      for (int fj = 0; fj < 4; ++fj)
        acc[fi][fj] = __builtin_amdgcn_mfma_f32_16x16x32_f16(a[fi], b[fj], acc[fi][fj], 0, 0, 0);
  };

  stage(0, 0);
  stage(1, 1);
  stage(2, 2);
  int t = 0;
  for (; t < ktiles - 3; ++t) {
    PHASE_WAIT(8);
    stage(t + 3, (t + 3) & 3);
    compute(t & 3);
  }
  PHASE_WAIT(8);
  compute(t & 3);
  ++t;
  PHASE_WAIT(4);
  compute(t & 3);
  ++t;
  PHASE_WAIT(0);
  compute(t & 3);

#pragma unroll
  for (int fi = 0; fi < 4; ++fi) {
#pragma unroll
    for (int fj = 0; fj < 4; ++fj) {
      int co = by * 128 + wr_ * 64 + fi * 16 + fc * 4;
      int px = bx * 128 + wc_ * 64 + fj * 16 + fr;
      size_t o = (size_t)px * Cout + co;
      if (OUTMODE == 4) {
        half_t* myp = (half_t*)pbuf + (size_t)bz * zstride;
        f16x4 hv;
#pragma unroll
        for (int j = 0; j < 4; ++j) hv[j] = f2h(acc[fi][fj][j]);
        *(f16x4*)&myp[o] = hv;
      } else {
        f32x4 bb = *(const f32x4*)&bias[co];
        f16x4 hv;
#pragma unroll
        for (int j = 0; j < 4; ++j) {
          float tt = acc[fi][fj][j] + bb[j];
          hv[j] = f2h(LEAKY(tt, slope));
        }
        *(f16x4*)&((half_t*)outp)[o] = hv;
      }
    }
  }

  if (OUTMODE == 4) {
    __threadfence();
    if (tid == 0) {
      unsigned c = __hip_atomic_fetch_add(cnt + (bx * Y + by), 1u,
                                          __ATOMIC_ACQ_REL, __HIP_MEMORY_SCOPE_AGENT);
      lastf = (c == (unsigned)(Z - 1)) ? 1u : 0u;
    }
    __syncthreads();
    if (!lastf) return;
    half_t* outh = (half_t*)outp;
#pragma unroll
    for (int fi = 0; fi < 4; ++fi) {
#pragma unroll
      for (int fj = 0; fj < 4; ++fj) {
        int co = by * 128 + wr_ * 64 + fi * 16 + fc * 4;
        int px = bx * 128 + wc_ * 64 + fj * 16 + fr;
        size_t o = (size_t)px * Cout + co;
        f32x4 s = *(const f32x4*)&bias[co];
        for (int z = 0; z < Z; ++z) {
          f16x4 pv = *(const f16x4*)&((half_t*)pbuf)[(size_t)z * zstride + o];
#pragma unroll
          for (int j = 0; j < 4; ++j) s[j] += (float)pv[j];
        }
        f16x4 hv;
#pragma unroll
        for (int j = 0; j < 4; ++j) hv[j] = f2h(LEAKY(s[j], slope));
        *(f16x4*)&outh[o] = hv;
      }
    }
  }
}

// ---------------- fused LSTM step + optional fc1 plane (round-11 proven) --------
__global__ __launch_bounds__(256) void lstm_fused(
    const half_t* __restrict__ h0in, half_t* __restrict__ h0out,
    const half_t* __restrict__ h1in, half_t* __restrict__ h1out,
    const half_t* __restrict__ wcat0, const half_t* __restrict__ wcat1,
    const float* __restrict__ xw0, const float* __restrict__ bg1,
    float* __restrict__ c0, float* __restrict__ c1,
    half_t* __restrict__ ysout, int zl1, int zfc,
    const half_t* __restrict__ fcw, const float* __restrict__ fcb,
    const half_t* __restrict__ fcin, half_t* __restrict__ fcout) {
  const int bzp = blockIdx.z;
  const bool isFC = (bzp == zfc);
  const bool isL1 = (bzp == zl1);
  if (isFC && blockIdx.y >= 8) return;
  const int NT = isL1 ? 16 : 8;
  const half_t* Asrc = isFC ? fcw : (isL1 ? wcat1 : wcat0);
  const int K = NT * 64;

  __shared__ half_t lds[4][8192];
  const int tid = threadIdx.x;
  const int lane = tid & 63, wid = tid >> 6;
  const int ybase = blockIdx.y * 64, bbase = blockIdx.x * 64;
  const int rA0 = wid * 16 + (lane >> 3);
  const int rA1 = rA0 + 8;
  const int chS = ((lane & 7) ^ ((lane >> 3) & 7)) * 8;
  const half_t* gA0 = Asrc + (size_t)(ybase + rA0) * K + chS;
  const half_t* gA1 = Asrc + (size_t)(ybase + rA1) * K + chS;
  const size_t hb0 = (size_t)(bbase + rA0) * 512 + chS;
  const size_t hb1 = (size_t)(bbase + rA1) * 512 + chS;
  const half_t* bsrc0 = isFC ? fcin : h0in;

  auto stage = [&](int t, int buf) {
    GLD(gA0 + t * 64, &lds[buf][wid * 1024]);
    GLD(gA1 + t * 64, &lds[buf][wid * 1024 + 512]);
    const half_t* hs = (isL1 && t >= 8) ? h1in : bsrc0;
    int koff = (isL1 && t >= 8) ? (t - 8) * 64 : t * 64;
    GLD(hs + hb0 + koff, &lds[buf][4096 + wid * 1024]);
    GLD(hs + hb1 + koff, &lds[buf][4096 + wid * 1024 + 512]);
  };

  const int fr = lane & 15, fc = lane >> 4;
  const int wr_ = wid & 1, wc_ = wid >> 1;

  f32x4 acc[2][2];
#pragma unroll
  for (int fi = 0; fi < 2; ++fi)
#pragma unroll
    for (int fj = 0; fj < 2; ++fj) acc[fi][fj] = (f32x4){0.f, 0.f, 0.f, 0.f};

  auto compute = [&](int buf) {
    const half_t* L = &lds[buf][0];
#pragma unroll
    for (int s = 0; s < 2; ++s) {
      f16x8 a[2], b[2];
#pragma unroll
      for (int fi = 0; fi < 2; ++fi) {
        int row = wr_ * 32 + fi * 16 + fr;
        a[fi] = *(const f16x8*)&L[row * 64 + (((s * 4 + fc) ^ (fr & 7)) * 8)];
      }
#pragma unroll
      for (int fj = 0; fj < 2; ++fj) {
        int brow = wc_ * 32 + fj * 16 + fr;
        b[fj] = *(const f16x8*)&L[4096 + brow * 64 + (((s * 4 + fc) ^ (fr & 7)) * 8)];
      }
#pragma unroll
      for (int fi = 0; fi < 2; ++fi)
#pragma unroll
        for (int fj = 0; fj < 2; ++fj)
          acc[fi][fj] = __builtin_amdgcn_mfma_f32_16x16x32_f16(a[fi], b[fj], acc[fi][fj], 0, 0, 0);
    }
  };

  stage(0, 0);
  stage(1, 1);
  stage(2, 2);
  int t = 0;
  for (; t < NT - 3; ++t) {
    PHASE_WAIT(8);
    stage(t + 3, (t + 3) & 3);
    compute(t & 3);
  }
  PHASE_WAIT(8);
  compute(t & 3);
  ++t;
  PHASE_WAIT(4);
  compute(t & 3);
  ++t;
  PHASE_WAIT(0);
  compute(t & 3);

  if (isFC) {
#pragma unroll
    for (int fi = 0; fi < 2; ++fi) {
#pragma unroll
      for (int fj = 0; fj < 2; ++fj) {
        int Rb = ybase + wr_ * 32 + fi * 16 + fc * 4;  // co base
        int b = bbase + wc_ * 32 + fj * 16 + fr;       // chunk-local row
        f32x4 bb = *(const f32x4*)&fcb[Rb];
        f16x4 hv;
#pragma unroll
        for (int j = 0; j < 4; ++j) {
          float tt = acc[fi][fj][j] + bb[j];
          hv[j] = f2h(LEAKY(tt, 0.01f));
        }
        *(f16x4*)&fcout[(size_t)b * 512 + Rb] = hv;
      }
    }
    return;
  }

  float* c = isL1 ? c1 : c0;
  half_t* hout = isL1 ? h1out : h0out;
#pragma unroll
  for (int fi = 0; fi < 2; ++fi) {
#pragma unroll
    for (int fj = 0; fj < 2; ++fj) {
      int Rb = ybase + wr_ * 32 + fi * 16 + fc * 4;
      int u = Rb >> 2;
      int b = bbase + wc_ * 32 + fj * 16 + fr;
      float p[4];
#pragma unroll
      for (int j = 0; j < 4; ++j) {
        float s = acc[fi][fj][j];
        s += isL1 ? bg1[j * 512 + u] : xw0[b * 2048 + j * 512 + u];
        p[j] = s;
      }
      int ci = b * 512 + u;
      float cprev = c[ci];
      float ig = sig_(p[0]);
      float fg = sig_(p[1]);
      float gg = tanhf(p[2]);
      float og = sig_(p[3]);
      float cn = fg * cprev + ig * gg;
      float hn = og * tanhf(cn);
      c[ci] = cn;
      hout[ci] = f2h(hn);
      if (isL1) ysout[ci] = f2h(hn);
    }
  }
}

// ---------------- final FC: sigmoid(fc1o @ fw2.T + fb2), [2560,13] ----------------
__global__ void fc2_sigmoid(const half_t* __restrict__ in, const float* __restrict__ w,
                            const float* __restrict__ b, float* __restrict__ out) {
  int idx = blockIdx.x * blockDim.x + threadIdx.x;
  if (idx >= 2560 * 13) return;
  int j = idx % 13, r = idx / 13;
  const half_t* ip = in + (size_t)r * 512;
  const float* wp = w + j * 512;
  float s = b[j];
  for (int k = 0; k < 512; k += 8) {
    f16x8 hv = *(const f16x8*)&ip[k];
#pragma unroll
    for (int q = 0; q < 8; ++q) s = fmaf((float)hv[q], wp[k + q], s);
  }
  out[idx] = sig_(s);
}

// ---------------- launch ----------------
extern "C" void kernel_launch(void* const* d_in, const int* in_sizes, int n_in,
                              void* d_out, int out_size, void* d_ws, size_t ws_size,
                              hipStream_t stream) {
  const float* x   = (const float*)d_in[0];
  const float* w1  = (const float*)d_in[1];  const float* b1 = (const float*)d_in[2];
  const float* w2  = (const float*)d_in[3];  const float* b2 = (const float*)d_in[4];
  const float* w3  = (const float*)d_in[5];  const float* b3 = (const float*)d_in[6];
  const float* w4  = (const float*)d_in[7];  const float* b4 = (const float*)d_in[8];
  const float* w5  = (const float*)d_in[9];  const float* b5 = (const float*)d_in[10];
  const float* wih0 = (const float*)d_in[11]; const float* whh0 = (const float*)d_in[12];
  const float* bih0 = (const float*)d_in[13]; const float* bhh0 = (const float*)d_in[14];
  const float* wih1 = (const float*)d_in[15]; const float* whh1 = (const float*)d_in[16];
  const float* bih1 = (const float*)d_in[17]; const float* bhh1 = (const float*)d_in[18];
  const float* fw1 = (const float*)d_in[19]; const float* fb1 = (const float*)d_in[20];
  const float* fw2 = (const float*)d_in[21]; const float* fb2 = (const float*)d_in[22];
  float* out = (float*)d_out;

  // ---- workspace layout (within 75.6 MB proven) ----
  float* bg0 = (float*)d_ws;                // 2048
  float* bg1 = bg0 + 2048;                  // 2048
  float* xw0 = bg1 + 2048;                  // 262144
  float* c0  = xw0 + 262144;                // 65536
  float* c1  = c0 + 65536;                  // 65536
  half_t* h0a = (half_t*)(c1 + 65536);      // 4 x 65536 halves
  half_t* h0b = h0a + 65536;
  half_t* h1a = h0b + 65536;
  half_t* h1b = h1a + 65536;
  half_t* BUF1 = h1b + 65536;               // 8,388,608  [A1 -> A3 -> feat]
  half_t* BUF2 = BUF1 + 8388608;            // 2,768,896  [A2 -> A4 -> ys+fc1o]
  half_t* w1r  = BUF2 + 2768896;            // 26,624
  half_t* w2r  = w1r + 26624;               // 401,408
  half_t* w3r  = w2r + 401408;              // 819,200
  half_t* w4r  = w3r + 819200;              // 3,276,800
  half_t* w5r  = w4r + 3276800;             // 6,553,600
  half_t* wih0h  = w5r + 6553600;           // 1,048,576
  half_t* wcat0h = wih0h + 1048576;         // 1,048,576
  half_t* wcat1h = wcat0h + 1048576;        // 2,097,152
  half_t* fw1h   = wcat1h + 2097152;        // 262,144
  unsigned* cntU = (unsigned*)(fw1h + 262144);  // 448 u32 (A:169 B:162 C:100 D:16)
  half_t* xpad   = (half_t*)(cntU + 448);   // union: xpad / partial buffers
  half_t* pbH = xpad;
  float* pbC = (float*)xpad;
  unsigned* cntA = cntU;
  unsigned* cntB = cntU + 169;
  unsigned* cntC = cntU + 331;
  unsigned* cntD = cntU + 431;

  half_t* A1 = BUF1;                        // [131072 px][64]
  half_t* A2 = BUF2;                        // [21632][128]
  half_t* A3 = BUF1;                        // [10368][256]
  half_t* A4 = BUF2;                        // [3200][512]  (A2 dead)
  half_t* feat = BUF1;                      // [128][512]   (A3 dead)
  half_t* ys   = BUF2;                      // [2560][512]  (A4 dead post-conv5)
  half_t* fc1o = BUF2 + 1310720;

  dim3 blk(256);

  // ---- prep (single launch: elementwise + weight transposes) ----
  prep_main<<<ELEM_BLOCKS + 1408, blk, 0, stream>>>(
      x, w1, w2, w3, w4, w5, wih0, whh0, bih0, bhh0, wih1, whh1, bih1, bhh1, fw1,
      bg0, bg1, c0, (unsigned*)h0a, cntU, xpad, w1r, w2r, w3r, w4r, w5r,
      wih0h, fw1h, wcat0h, wcat1h);

  // ---- conv stack (split-K with in-kernel fixup; no finalize launches) ----
  conv_mfma<7, 2, 3, 0><<<dim3(2048, 1, 1), blk, 0, stream>>>(
      xpad, w1r, b1, A1, 70, 70, 32, 32, 64, 416, 13, 0.2f, 0, nullptr, nullptr, 0);
  conv_mfma128<7, 2, 6, 4><<<338, blk, 0, stream>>>(
      A1, w2r, b2, A2, 32, 32, 13, 13, 128, 3136, 49, 0.2f, 2768896LL, 1, 2,
      pbH, cntA, 2);
  conv_mfma128<5, 1, 7, 4><<<324, blk, 0, stream>>>(
      A2, w3r, b3, A3, 13, 13, 9, 9, 256, 3200, 50, 0.2f, 2654208LL, 2, 4,
      pbH, cntB, 2);
  conv_mfma128<5, 1, 8, 4><<<400, blk, 0, stream>>>(
      A3, w4r, b4, A4, 9, 9, 5, 5, 512, 6400, 50, 0.2f, 1638400LL, 4, 16,
      pbH, cntC, 4);
  conv_mfma<5, 1, 9, 4><<<dim3(2, 8, 25), blk, 0, stream>>>(
      A4, w5r, b5, feat, 5, 5, 1, 1, 512, 12800, 16, 0.2f, 65536LL,
      pbC, cntD, 25);

  // xw0 = feat @ wih0.T + bg0  [128][2048] f32 (slope=1 -> identity)
  conv_mfma<1, 1, 9, 1><<<dim3(2, 32, 1), blk, 0, stream>>>(
      feat, wih0h, bg0, xw0, 1, 1, 1, 1, 2048, 512, 16, 1.0f, 0, nullptr, nullptr, 0);

  // ---- 2-layer LSTM, 20 steps, fused l0(t+1)||l1(t)||fc1(chunk t-3) ----
  half_t* h0buf[2] = {h0a, h0b};
  half_t* h1buf[2] = {h1a, h1b};
  lstm_fused<<<dim3(2, 32, 1), blk, 0, stream>>>(
      h0a, h0b, h1a, h1a, wcat0h, wcat1h, xw0, bg1, c0, c1, ys,
      -1, -1, fw1h, fb1, nullptr, nullptr);
  lstm_fused<<<dim3(2, 32, 2), blk, 0, stream>>>(
      h0buf[1], h0buf[0], h1buf[0], h1buf[1], wcat0h, wcat1h, xw0, bg1, c0, c1,
      ys, 1, -1, fw1h, fb1, nullptr, nullptr);
  for (int t = 3; t <= 20; ++t) {
    lstm_fused<<<dim3(2, 32, 3), blk, 0, stream>>>(
        h0buf[(t - 1) & 1], h0buf[t & 1], h1buf[t & 1], h1buf[(t - 1) & 1],
        wcat0h, wcat1h, xw0, bg1, c0, c1, ys + (size_t)(t - 2) * 65536,
        1, 2, fw1h, fb1, ys + (size_t)(t - 3) * 65536, fc1o + (size_t)(t - 3) * 65536);
  }
  lstm_fused<<<dim3(2, 32, 2), blk, 0, stream>>>(
      h0buf[0], h0buf[1], h1buf[1], h1buf[0],
      wcat0h, wcat1h, xw0, bg1, c0, c1, ys + (size_t)19 * 65536,
      0, 1, fw1h, fb1, ys + (size_t)18 * 65536, fc1o + (size_t)18 * 65536);

  // ---- FC head tail: fc1 chunk 19, then fc2 ----
  conv_mfma<1, 1, 9, 0><<<dim3(2, 8, 1), blk, 0, stream>>>(
      ys + (size_t)19 * 65536, fw1h, fb1, fc1o + (size_t)19 * 65536,
      1, 1, 1, 1, 512, 512, 16, 0.01f, 0, nullptr, nullptr, 0);
  fc2_sigmoid<<<130, blk, 0, stream>>>(fc1o, fw2, fb2, out);
}

// Round 14
// 401.553 us; speedup vs baseline: 1.7420x; 1.7420x over previous
//
#include <hip/hip_runtime.h>
#include <math.h>

typedef _Float16 half_t;
typedef __attribute__((ext_vector_type(8))) _Float16 f16x8;
typedef __attribute__((ext_vector_type(4))) _Float16 f16x4;
typedef __attribute__((ext_vector_type(4))) float f32x4;

#define LEAKY(v, s) ((v) >= 0.f ? (v) : (s) * (v))

__device__ __forceinline__ float sig_(float x) { return 1.f / (1.f + expf(-x)); }
__device__ __forceinline__ half_t f2h(float f) { return (half_t)f; }

#define GLD(gp, lp)                                              \
  __builtin_amdgcn_global_load_lds(                              \
      (const __attribute__((address_space(1))) void*)(gp),       \
      (__attribute__((address_space(3))) void*)(lp), 16, 0, 0)

#define PHASE_WAIT(N)                                            \
  asm volatile("s_waitcnt vmcnt(" #N ")" ::: "memory");          \
  __builtin_amdgcn_s_barrier();                                  \
  __builtin_amdgcn_sched_barrier(0)

// ---------------- merged prep: elementwise segments + LDS-bounce transposes ----
// bg0c/bg1c and wih0c use LSTM "cat" order: row r = u*4+g.
#define R0 2048LL      // bg0c
#define R1 4096LL      // bg1c
#define R2 135168LL    // c zero (131072 f32)
#define R3 266240LL    // h zero (131072 u32)
#define R4 5283840LL   // pad_x (5017600)
#define R5 5310464LL   // w1r (26624)
#define R6 6359040LL   // wih0c (1048576)
#define R7 6621184LL   // fw1h (262144)
#define R8 7669760LL   // wcat0 (1048576)
#define R9 9766912LL   // wcat1 end
#define ELEM_BLOCKS 38152

__global__ __launch_bounds__(256) void prep_main(
    const float* __restrict__ x, const float* __restrict__ w1,
    const float* __restrict__ w2, const float* __restrict__ w3,
    const float* __restrict__ w4, const float* __restrict__ w5,
    const float* __restrict__ wih0, const float* __restrict__ whh0,
    const float* __restrict__ bih0, const float* __restrict__ bhh0,
    const float* __restrict__ wih1, const float* __restrict__ whh1,
    const float* __restrict__ bih1, const float* __restrict__ bhh1,
    const float* __restrict__ fw1,
    float* __restrict__ bg0c, float* __restrict__ bg1c,
    float* __restrict__ czero, unsigned* __restrict__ hzero,
    half_t* __restrict__ xpad, half_t* __restrict__ w1r,
    half_t* __restrict__ w2r, half_t* __restrict__ w3r,
    half_t* __restrict__ w4r, half_t* __restrict__ w5r,
    half_t* __restrict__ wih0c, half_t* __restrict__ fw1h,
    half_t* __restrict__ wcat0h, half_t* __restrict__ wcat1h) {
  __shared__ float T[12800];
  const int tid = threadIdx.x;
  if (blockIdx.x >= ELEM_BLOCKS) {
    int bid = blockIdx.x - ELEM_BLOCKS;
    const float* W;
    half_t* D;
    int co, Cin, TAP, lg2;
    if (bid < 128) {
      W = w2; D = w2r; co = bid; Cin = 64; TAP = 49; lg2 = 6;
    } else if (bid < 384) {
      W = w3; D = w3r; co = bid - 128; Cin = 128; TAP = 25; lg2 = 7;
    } else if (bid < 896) {
      W = w4; D = w4r; co = bid - 384; Cin = 256; TAP = 25; lg2 = 8;
    } else {
      W = w5; D = w5r; co = bid - 896; Cin = 512; TAP = 25; lg2 = 9;
    }
    int n = Cin * TAP;
    const float* src = W + (size_t)co * n;
    for (int i = tid; i < n; i += 256) T[i] = src[i];
    __syncthreads();
    half_t* dst = D + (size_t)co * n;
    for (int j = tid; j < n; j += 256) {
      int ci = j & (Cin - 1);
      int tap = j >> lg2;
      dst[j] = f2h(T[ci * TAP + tap]);
    }
    return;
  }
  long long i = (long long)blockIdx.x * 256 + tid;
  if (i < R0) {
    int j = (int)i;
    int u = j >> 2, g = j & 3;
    bg0c[j] = bih0[g * 512 + u] + bhh0[g * 512 + u];
  } else if (i < R1) {
    int j = (int)(i - R0);
    int u = j >> 2, g = j & 3;
    bg1c[j] = bih1[g * 512 + u] + bhh1[g * 512 + u];
  } else if (i < R2) {
    czero[i - R1] = 0.f;
  } else if (i < R3) {
    hzero[i - R2] = 0u;
  } else if (i < R4) {
    long long j = i - R3;
    int c = j & 7;
    long long t = j >> 3;
    int iw = t % 70; t /= 70;
    int ih = t % 70;
    int n = t / 70;
    float v = 0.f;
    if (c < 3 && ih >= 3 && ih < 67 && iw >= 3 && iw < 67)
      v = x[((n * 3 + c) * 64 + (ih - 3)) * 64 + (iw - 3)];
    xpad[j] = f2h(v);
  } else if (i < R5) {
    int j = (int)(i - R4);
    int kg = j % 416, co = j / 416;
    int ci = kg & 7, tap = kg >> 3;
    float v = 0.f;
    if (tap < 49 && ci < 3) {
      int kh = tap / 7, kw = tap % 7;
      v = w1[((co * 3 + ci) * 7 + kh) * 7 + kw];
    }
    w1r[j] = f2h(v);
  } else if (i < R6) {
    int j = (int)(i - R5);
    int r = j >> 9, k = j & 511;
    int u = r >> 2, g = r & 3;
    wih0c[j] = f2h(wih0[(g * 512 + u) * 512 + k]);
  } else if (i < R7) {
    int j = (int)(i - R6);
    fw1h[j] = f2h(fw1[j]);
  } else if (i < R8) {
    int j = (int)(i - R7);
    int r = j >> 9, k = j & 511;
    int u = r >> 2, g = r & 3;
    wcat0h[j] = f2h(whh0[(g * 512 + u) * 512 + k]);
  } else if (i < R9) {
    int j = (int)(i - R8);
    int r = j >> 10, k = j & 1023;
    int u = r >> 2, g = r & 3;
    int row = g * 512 + u;
    wcat1h[j] = f2h(k < 512 ? wih1[row * 512 + k] : whh1[row * 512 + (k - 512)]);
  }
}

// ---------------- 64x64 fp16 MFMA conv / GEMM ----------------
// OUTMODE: 0 fp16+bias+leaky; 2 f32 raw partial at z*zstride.
template <int KW, int S, int LOG2CIN, int OUTMODE>
__global__ __launch_bounds__(256) void conv_mfma(
    const half_t* __restrict__ xin, const half_t* __restrict__ wr,
    const float* __restrict__ bias, void* __restrict__ outp,
    int Hin, int Win, int Hout, int Wout, int Cout, int K, int ktiles, float slope,
    long long zstride) {
  constexpr int CIN = 1 << LOG2CIN;
  __shared__ half_t lds[4][4096];
  const int tid = threadIdx.x;
  const int lane = tid & 63, wid = tid >> 6;
  const int sRow = tid >> 2, sCh = tid & 3;
  const int sSwz = sCh ^ ((sRow ^ (sRow >> 2)) & 3);
  const int kt0 = blockIdx.z * ktiles;
  const half_t* gArow = wr + (size_t)(blockIdx.y * 64 + sRow) * K + sSwz * 8;
  int p = blockIdx.x * 64 + sRow;
  int hw = Hout * Wout;
  int n = p / hw;
  int rem = p - n * hw;
  int oh = rem / Wout;
  int ow = rem - oh * Wout;
  const half_t* xb = xin + ((size_t)(n * Hin + oh * S) * Win + ow * S) * CIN;
  const int fr = lane & 15, fc = lane >> 4;
  const int r0 = (wid & 1) * 32, c0 = (wid >> 1) * 32;
  const int sw = (fc ^ ((fr ^ (fr >> 2)) & 3)) * 8;
  const int ia0 = (r0 + fr) * 32 + sw;
  const int ia1 = (r0 + 16 + fr) * 32 + sw;
  const int ib0 = 2048 + (c0 + fr) * 32 + sw;
  const int ib1 = 2048 + (c0 + 16 + fr) * 32 + sw;

  auto stage = [&](int t, int buf) {
    GLD(gArow + (size_t)(kt0 + t) * 32, &lds[buf][wid * 512]);
    int kg = (kt0 + t) * 32 + sSwz * 8;
    int ci = kg & (CIN - 1);
    int tap = kg >> LOG2CIN;
    int kh = tap / KW, kw = tap - kh * KW;
    GLD(xb + (kh * Win + kw) * CIN + ci, &lds[buf][2048 + wid * 512]);
  };

  f32x4 acc00 = {0.f, 0.f, 0.f, 0.f};
  f32x4 acc01 = acc00, acc10 = acc00, acc11 = acc00;

  auto compute = [&](int buf) {
    const half_t* L = &lds[buf][0];
    f16x8 a0 = *(const f16x8*)&L[ia0];
    f16x8 a1 = *(const f16x8*)&L[ia1];
    f16x8 b0 = *(const f16x8*)&L[ib0];
    f16x8 b1 = *(const f16x8*)&L[ib1];
    acc00 = __builtin_amdgcn_mfma_f32_16x16x32_f16(a0, b0, acc00, 0, 0, 0);
    acc01 = __builtin_amdgcn_mfma_f32_16x16x32_f16(a0, b1, acc01, 0, 0, 0);
    acc10 = __builtin_amdgcn_mfma_f32_16x16x32_f16(a1, b0, acc10, 0, 0, 0);
    acc11 = __builtin_amdgcn_mfma_f32_16x16x32_f16(a1, b1, acc11, 0, 0, 0);
  };

  stage(0, 0);
  stage(1, 1);
  stage(2, 2);
  int t = 0;
  for (; t < ktiles - 3; ++t) {
    PHASE_WAIT(4);
    stage(t + 3, (t + 3) & 3);
    compute(t & 3);
  }
  PHASE_WAIT(4);
  compute(t & 3);
  ++t;
  PHASE_WAIT(2);
  compute(t & 3);
  ++t;
  PHASE_WAIT(0);
  compute(t & 3);

#pragma unroll
  for (int am = 0; am < 2; ++am) {
#pragma unroll
    for (int bn = 0; bn < 2; ++bn) {
      f32x4 a = am == 0 ? (bn == 0 ? acc00 : acc01) : (bn == 0 ? acc10 : acc11);
      int co = blockIdx.y * 64 + r0 + am * 16 + fc * 4;
      int px = blockIdx.x * 64 + c0 + bn * 16 + fr;
      size_t o = (size_t)px * Cout + co;
      if (OUTMODE == 2) {
        float* pb = (float*)outp + (size_t)blockIdx.z * zstride;
        *(f32x4*)&pb[o] = a;
      } else {
        f32x4 bb = *(const f32x4*)&bias[co];
        f16x4 hv;
#pragma unroll
        for (int j = 0; j < 4; ++j) {
          float tt = a[j] + bb[j];
          hv[j] = f2h(LEAKY(tt, slope));
        }
        *(f16x4*)&((half_t*)outp)[o] = hv;
      }
    }
  }
}

// ---------------- 128x128 fp16 MFMA conv, XCD-swizzled 1D grid ----------------
// OUTMODE: 0 fp16+bias+leaky; 3 fp16 raw partial at bz*zstride.
template <int KW, int S, int LOG2CIN, int OUTMODE>
__global__ __launch_bounds__(256) void conv_mfma128(
    const half_t* __restrict__ xin, const half_t* __restrict__ wr,
    const float* __restrict__ bias, void* __restrict__ outp,
    int Hin, int Win, int Hout, int Wout, int Cout, int K, int ktiles, float slope,
    long long zstride, int Y, int G) {
  constexpr int CIN = 1 << LOG2CIN;
  __shared__ half_t lds[4][8192];
  const int L = blockIdx.x;
  const int bx = L / G;
  const int g = L % G;
  const int by = g % Y;
  const int bz = g / Y;
  const int tid = threadIdx.x;
  const int lane = tid & 63, wid = tid >> 6;
  const int sRow = tid >> 2, sCh = tid & 3;
  const int sSwz = sCh ^ ((sRow ^ (sRow >> 2)) & 3);
  const int kt0 = bz * ktiles;
  const half_t* gA0 = wr + (size_t)(by * 128 + sRow) * K + sSwz * 8;
  const half_t* gA1 = wr + (size_t)(by * 128 + 64 + sRow) * K + sSwz * 8;
  int hw = Hout * Wout;
  int p0 = bx * 128 + sRow;
  int n0 = p0 / hw, r0p = p0 - n0 * hw, oh0 = r0p / Wout, ow0 = r0p - oh0 * Wout;
  const half_t* xb0 = xin + ((size_t)(n0 * Hin + oh0 * S) * Win + ow0 * S) * CIN;
  int p1 = p0 + 64;
  int n1 = p1 / hw, r1p = p1 - n1 * hw, oh1 = r1p / Wout, ow1 = r1p - oh1 * Wout;
  const half_t* xb1 = xin + ((size_t)(n1 * Hin + oh1 * S) * Win + ow1 * S) * CIN;

  const int fr = lane & 15, fc = lane >> 4;
  const int wr_ = wid & 1, wc_ = wid >> 1;
  const int sw = (fc ^ ((fr ^ (fr >> 2)) & 3)) * 8;
  const int iaB = (wr_ * 64 + fr) * 32 + sw;
  const int ibB = 4096 + (wc_ * 64 + fr) * 32 + sw;

  auto stage = [&](int t, int buf) {
    half_t* LB = &lds[buf][0];
    GLD(gA0 + (size_t)(kt0 + t) * 32, LB + wid * 512);
    GLD(gA1 + (size_t)(kt0 + t) * 32, LB + 2048 + wid * 512);
    int kg = (kt0 + t) * 32 + sSwz * 8;
    int ci = kg & (CIN - 1);
    int tap = kg >> LOG2CIN;
    int kh = tap / KW, kw = tap - kh * KW;
    int xoff = (kh * Win + kw) * CIN + ci;
    GLD(xb0 + xoff, LB + 4096 + wid * 512);
    GLD(xb1 + xoff, LB + 6144 + wid * 512);
  };

  f32x4 acc[4][4];
#pragma unroll
  for (int i = 0; i < 4; ++i)
#pragma unroll
    for (int j = 0; j < 4; ++j) acc[i][j] = (f32x4){0.f, 0.f, 0.f, 0.f};

  auto compute = [&](int buf) {
    const half_t* L2 = &lds[buf][0];
    f16x8 a[4], b[4];
#pragma unroll
    for (int fi = 0; fi < 4; ++fi) a[fi] = *(const f16x8*)&L2[iaB + fi * 512];
#pragma unroll
    for (int fj = 0; fj < 4; ++fj) b[fj] = *(const f16x8*)&L2[ibB + fj * 512];
#pragma unroll
    for (int fi = 0; fi < 4; ++fi)
#pragma unroll
      for (int fj = 0; fj < 4; ++fj)
        acc[fi][fj] = __builtin_amdgcn_mfma_f32_16x16x32_f16(a[fi], b[fj], acc[fi][fj], 0, 0, 0);
  };

  stage(0, 0);
  stage(1, 1);
  stage(2, 2);
  int t = 0;
  for (; t < ktiles - 3; ++t) {
    PHASE_WAIT(8);
    stage(t + 3, (t + 3) & 3);
    compute(t & 3);
  }
  PHASE_WAIT(8);
  compute(t & 3);
  ++t;
  PHASE_WAIT(4);
  compute(t & 3);
  ++t;
  PHASE_WAIT(0);
  compute(t & 3);

#pragma unroll
  for (int fi = 0; fi < 4; ++fi) {
#pragma unroll
    for (int fj = 0; fj < 4; ++fj) {
      int co = by * 128 + wr_ * 64 + fi * 16 + fc * 4;
      int px = bx * 128 + wc_ * 64 + fj * 16 + fr;
      size_t o = (size_t)px * Cout + co;
      if (OUTMODE == 3) {
        half_t* pb = (half_t*)outp + (size_t)bz * zstride;
        f16x4 hv;
#pragma unroll
        for (int j = 0; j < 4; ++j) hv[j] = f2h(acc[fi][fj][j]);
        *(f16x4*)&pb[o] = hv;
      } else {
        f32x4 bb = *(const f32x4*)&bias[co];
        f16x4 hv;
#pragma unroll
        for (int j = 0; j < 4; ++j) {
          float tt = acc[fi][fj][j] + bb[j];
          hv[j] = f2h(LEAKY(tt, slope));
        }
        *(f16x4*)&((half_t*)outp)[o] = hv;
      }
    }
  }
}

// reduce K-split f32 partials (conv5)
__global__ void finalize_part(const float* __restrict__ pb, const float* __restrict__ bias,
                              half_t* __restrict__ out, int size, int nz) {
  int i = blockIdx.x * blockDim.x + threadIdx.x;
  if (i >= size) return;
  float s = bias[i & 511];
  for (int z = 0; z < nz; ++z) s += pb[(size_t)z * size + i];
  out[i] = f2h(LEAKY(s, 0.2f));
}

// reduce fp16 K-split partials, vectorized x8
__global__ void finalize_h(const half_t* __restrict__ pb, const float* __restrict__ bias,
                           half_t* __restrict__ out, int size8, int nz, int cmask,
                           long long zstride) {
  int idx = blockIdx.x * blockDim.x + threadIdx.x;
  if (idx >= size8) return;
  long long i = (long long)idx * 8;
  float s[8];
#pragma unroll
  for (int q = 0; q < 8; ++q) s[q] = bias[(int)((i + q) & cmask)];
  for (int z = 0; z < nz; ++z) {
    f16x8 v = *(const f16x8*)&pb[(size_t)z * zstride + i];
#pragma unroll
    for (int q = 0; q < 8; ++q) s[q] += (float)v[q];
  }
  f16x8 o;
#pragma unroll
  for (int q = 0; q < 8; ++q) o[q] = f2h(LEAKY(s[q], 0.2f));
  *(f16x8*)&out[i] = o;
}

// ---------------- LSTM step 1: xw0c = feat@wih0c^T + bg0c, gates -> h0_1, c0 ----
// h0_0 = 0 so step-1 pre-activation IS xw0c; fuse both into one kernel.
__global__ __launch_bounds__(256) void lstm0_step(
    const half_t* __restrict__ feat, const half_t* __restrict__ wih0c,
    const float* __restrict__ bg0c, float* __restrict__ xw0c,
    float* __restrict__ c0, half_t* __restrict__ h0out) {
  __shared__ half_t lds[4][8192];
  const int tid = threadIdx.x;
  const int lane = tid & 63, wid = tid >> 6;
  const int ybase = blockIdx.y * 64, bbase = blockIdx.x * 64;
  const int rA0 = wid * 16 + (lane >> 3);
  const int rA1 = rA0 + 8;
  const int chS = ((lane & 7) ^ ((lane >> 3) & 7)) * 8;
  const half_t* gA0 = wih0c + (size_t)(ybase + rA0) * 512 + chS;
  const half_t* gA1 = wih0c + (size_t)(ybase + rA1) * 512 + chS;
  const size_t hb0 = (size_t)(bbase + rA0) * 512 + chS;
  const size_t hb1 = (size_t)(bbase + rA1) * 512 + chS;

  auto stage = [&](int t, int buf) {
    GLD(gA0 + t * 64, &lds[buf][wid * 1024]);
    GLD(gA1 + t * 64, &lds[buf][wid * 1024 + 512]);
    GLD(feat + hb0 + t * 64, &lds[buf][4096 + wid * 1024]);
    GLD(feat + hb1 + t * 64, &lds[buf][4096 + wid * 1024 + 512]);
  };

  const int fr = lane & 15, fc = lane >> 4;
  const int wr_ = wid & 1, wc_ = wid >> 1;

  f32x4 acc[2][2];
#pragma unroll
  for (int fi = 0; fi < 2; ++fi)
#pragma unroll
    for (int fj = 0; fj < 2; ++fj) acc[fi][fj] = (f32x4){0.f, 0.f, 0.f, 0.f};

  auto compute = [&](int buf) {
    const half_t* L = &lds[buf][0];
#pragma unroll
    for (int s = 0; s < 2; ++s) {
      f16x8 a[2], b[2];
#pragma unroll
      for (int fi = 0; fi < 2; ++fi) {
        int row = wr_ * 32 + fi * 16 + fr;
        a[fi] = *(const f16x8*)&L[row * 64 + (((s * 4 + fc) ^ (fr & 7)) * 8)];
      }
#pragma unroll
      for (int fj = 0; fj < 2; ++fj) {
        int brow = wc_ * 32 + fj * 16 + fr;
        b[fj] = *(const f16x8*)&L[4096 + brow * 64 + (((s * 4 + fc) ^ (fr & 7)) * 8)];
      }
#pragma unroll
      for (int fi = 0; fi < 2; ++fi)
#pragma unroll
        for (int fj = 0; fj < 2; ++fj)
          acc[fi][fj] = __builtin_amdgcn_mfma_f32_16x16x32_f16(a[fi], b[fj], acc[fi][fj], 0, 0, 0);
    }
  };

  stage(0, 0);
  stage(1, 1);
  stage(2, 2);
  int t = 0;
  for (; t < 5; ++t) {
    PHASE_WAIT(8);
    stage(t + 3, (t + 3) & 3);
    compute(t & 3);
  }
  PHASE_WAIT(8);
  compute(5 & 3);
  PHASE_WAIT(4);
  compute(6 & 3);
  PHASE_WAIT(0);
  compute(7 & 3);

#pragma unroll
  for (int fi = 0; fi < 2; ++fi) {
#pragma unroll
    for (int fj = 0; fj < 2; ++fj) {
      int Rb = ybase + wr_ * 32 + fi * 16 + fc * 4;  // row = u*4+g, gate = j
      int u = Rb >> 2;
      int b = bbase + wc_ * 32 + fj * 16 + fr;
      f32x4 bb = *(const f32x4*)&bg0c[Rb];
      f32x4 pre;
#pragma unroll
      for (int j = 0; j < 4; ++j) pre[j] = acc[fi][fj][j] + bb[j];
      *(f32x4*)&xw0c[(size_t)b * 2048 + Rb] = pre;
      float ig = sig_(pre[0]);
      float gg = tanhf(pre[2]);
      float og = sig_(pre[3]);
      float cn = ig * gg;  // c_prev = 0
      float hn = og * tanhf(cn);
      int ci = b * 512 + u;
      c0[ci] = cn;
      h0out[ci] = f2h(hn);
    }
  }
}

// ---------------- fused LSTM step + optional fc1 plane ----------------
// z-planes: zl1 -> layer1, zfc -> fc1 on a ys chunk; others -> layer0.
// xw0c/bg1c are in (u*4+g) order -> epilogue base is one f32x4 load.
__global__ __launch_bounds__(256) void lstm_fused(
    const half_t* __restrict__ h0in, half_t* __restrict__ h0out,
    const half_t* __restrict__ h1in, half_t* __restrict__ h1out,
    const half_t* __restrict__ wcat0, const half_t* __restrict__ wcat1,
    const float* __restrict__ xw0c, const float* __restrict__ bg1c,
    float* __restrict__ c0, float* __restrict__ c1,
    half_t* __restrict__ ysout, int zl1, int zfc,
    const half_t* __restrict__ fcw, const float* __restrict__ fcb,
    const half_t* __restrict__ fcin, half_t* __restrict__ fcout) {
  const int bzp = blockIdx.z;
  const bool isFC = (bzp == zfc);
  const bool isL1 = (bzp == zl1);
  if (isFC && blockIdx.y >= 8) return;
  const int NT = isL1 ? 16 : 8;
  const half_t* Asrc = isFC ? fcw : (isL1 ? wcat1 : wcat0);
  const int K = NT * 64;

  __shared__ half_t lds[4][8192];
  const int tid = threadIdx.x;
  const int lane = tid & 63, wid = tid >> 6;
  const int ybase = blockIdx.y * 64, bbase = blockIdx.x * 64;
  const int rA0 = wid * 16 + (lane >> 3);
  const int rA1 = rA0 + 8;
  const int chS = ((lane & 7) ^ ((lane >> 3) & 7)) * 8;
  const half_t* gA0 = Asrc + (size_t)(ybase + rA0) * K + chS;
  const half_t* gA1 = Asrc + (size_t)(ybase + rA1) * K + chS;
  const size_t hb0 = (size_t)(bbase + rA0) * 512 + chS;
  const size_t hb1 = (size_t)(bbase + rA1) * 512 + chS;
  const half_t* bsrc0 = isFC ? fcin : h0in;

  auto stage = [&](int t, int buf) {
    GLD(gA0 + t * 64, &lds[buf][wid * 1024]);
    GLD(gA1 + t * 64, &lds[buf][wid * 1024 + 512]);
    const half_t* hs = (isL1 && t >= 8) ? h1in : bsrc0;
    int koff = (isL1 && t >= 8) ? (t - 8) * 64 : t * 64;
    GLD(hs + hb0 + koff, &lds[buf][4096 + wid * 1024]);
    GLD(hs + hb1 + koff, &lds[buf][4096 + wid * 1024 + 512]);
  };

  const int fr = lane & 15, fc = lane >> 4;
  const int wr_ = wid & 1, wc_ = wid >> 1;

  f32x4 acc[2][2];
#pragma unroll
  for (int fi = 0; fi < 2; ++fi)
#pragma unroll
    for (int fj = 0; fj < 2; ++fj) acc[fi][fj] = (f32x4){0.f, 0.f, 0.f, 0.f};

  auto compute = [&](int buf) {
    const half_t* L = &lds[buf][0];
#pragma unroll
    for (int s = 0; s < 2; ++s) {
      f16x8 a[2], b[2];
#pragma unroll
      for (int fi = 0; fi < 2; ++fi) {
        int row = wr_ * 32 + fi * 16 + fr;
        a[fi] = *(const f16x8*)&L[row * 64 + (((s * 4 + fc) ^ (fr & 7)) * 8)];
      }
#pragma unroll
      for (int fj = 0; fj < 2; ++fj) {
        int brow = wc_ * 32 + fj * 16 + fr;
        b[fj] = *(const f16x8*)&L[4096 + brow * 64 + (((s * 4 + fc) ^ (fr & 7)) * 8)];
      }
#pragma unroll
      for (int fi = 0; fi < 2; ++fi)
#pragma unroll
        for (int fj = 0; fj < 2; ++fj)
          acc[fi][fj] = __builtin_amdgcn_mfma_f32_16x16x32_f16(a[fi], b[fj], acc[fi][fj], 0, 0, 0);
    }
  };

  stage(0, 0);
  stage(1, 1);
  stage(2, 2);
  int t = 0;
  for (; t < NT - 3; ++t) {
    PHASE_WAIT(8);
    stage(t + 3, (t + 3) & 3);
    compute(t & 3);
  }
  PHASE_WAIT(8);
  compute(t & 3);
  ++t;
  PHASE_WAIT(4);
  compute(t & 3);
  ++t;
  PHASE_WAIT(0);
  compute(t & 3);

  if (isFC) {
#pragma unroll
    for (int fi = 0; fi < 2; ++fi) {
#pragma unroll
      for (int fj = 0; fj < 2; ++fj) {
        int Rb = ybase + wr_ * 32 + fi * 16 + fc * 4;  // co base
        int b = bbase + wc_ * 32 + fj * 16 + fr;       // chunk-local row
        f32x4 bb = *(const f32x4*)&fcb[Rb];
        f16x4 hv;
#pragma unroll
        for (int j = 0; j < 4; ++j) {
          float tt = acc[fi][fj][j] + bb[j];
          hv[j] = f2h(LEAKY(tt, 0.01f));
        }
        *(f16x4*)&fcout[(size_t)b * 512 + Rb] = hv;
      }
    }
    return;
  }

  float* c = isL1 ? c1 : c0;
  half_t* hout = isL1 ? h1out : h0out;
#pragma unroll
  for (int fi = 0; fi < 2; ++fi) {
#pragma unroll
    for (int fj = 0; fj < 2; ++fj) {
      int Rb = ybase + wr_ * 32 + fi * 16 + fc * 4;  // row = u*4+g, gate = j
      int u = Rb >> 2;
      int b = bbase + wc_ * 32 + fj * 16 + fr;
      f32x4 bb = isL1 ? *(const f32x4*)&bg1c[Rb]
                      : *(const f32x4*)&xw0c[(size_t)b * 2048 + Rb];
      float p[4];
#pragma unroll
      for (int j = 0; j < 4; ++j) p[j] = acc[fi][fj][j] + bb[j];
      int ci = b * 512 + u;
      float cprev = c[ci];
      float ig = sig_(p[0]);
      float fg = sig_(p[1]);
      float gg = tanhf(p[2]);
      float og = sig_(p[3]);
      float cn = fg * cprev + ig * gg;
      float hn = og * tanhf(cn);
      c[ci] = cn;
      hout[ci] = f2h(hn);
      if (isL1) ysout[ci] = f2h(hn);
    }
  }
}

// ---------------- final FC: sigmoid(fc1o @ fw2.T + fb2), [2560,13] ----------------
__global__ void fc2_sigmoid(const half_t* __restrict__ in, const float* __restrict__ w,
                            const float* __restrict__ b, float* __restrict__ out) {
  int idx = blockIdx.x * blockDim.x + threadIdx.x;
  if (idx >= 2560 * 13) return;
  int j = idx % 13, r = idx / 13;
  const half_t* ip = in + (size_t)r * 512;
  const float* wp = w + j * 512;
  float s = b[j];
  for (int k = 0; k < 512; k += 8) {
    f16x8 hv = *(const f16x8*)&ip[k];
#pragma unroll
    for (int q = 0; q < 8; ++q) s = fmaf((float)hv[q], wp[k + q], s);
  }
  out[idx] = sig_(s);
}

// ---------------- launch ----------------
extern "C" void kernel_launch(void* const* d_in, const int* in_sizes, int n_in,
                              void* d_out, int out_size, void* d_ws, size_t ws_size,
                              hipStream_t stream) {
  const float* x   = (const float*)d_in[0];
  const float* w1  = (const float*)d_in[1];  const float* b1 = (const float*)d_in[2];
  const float* w2  = (const float*)d_in[3];  const float* b2 = (const float*)d_in[4];
  const float* w3  = (const float*)d_in[5];  const float* b3 = (const float*)d_in[6];
  const float* w4  = (const float*)d_in[7];  const float* b4 = (const float*)d_in[8];
  const float* w5  = (const float*)d_in[9];  const float* b5 = (const float*)d_in[10];
  const float* wih0 = (const float*)d_in[11]; const float* whh0 = (const float*)d_in[12];
  const float* bih0 = (const float*)d_in[13]; const float* bhh0 = (const float*)d_in[14];
  const float* wih1 = (const float*)d_in[15]; const float* whh1 = (const float*)d_in[16];
  const float* bih1 = (const float*)d_in[17]; const float* bhh1 = (const float*)d_in[18];
  const float* fw1 = (const float*)d_in[19]; const float* fb1 = (const float*)d_in[20];
  const float* fw2 = (const float*)d_in[21]; const float* fb2 = (const float*)d_in[22];
  float* out = (float*)d_out;

  // ---- workspace layout (within 75.6 MB proven) ----
  float* bg0c = (float*)d_ws;               // 2048
  float* bg1c = bg0c + 2048;                // 2048
  float* xw0c = bg1c + 2048;                // 262144
  float* c0  = xw0c + 262144;               // 65536
  float* c1  = c0 + 65536;                  // 65536
  half_t* h0a = (half_t*)(c1 + 65536);      // 4 x 65536 halves
  half_t* h0b = h0a + 65536;
  half_t* h1a = h0b + 65536;
  half_t* h1b = h1a + 65536;
  half_t* BUF1 = h1b + 65536;               // 8,388,608  [A1 -> A3 -> feat]
  half_t* BUF2 = BUF1 + 8388608;            // 2,768,896  [A2 -> A4 -> ys+fc1o]
  half_t* w1r  = BUF2 + 2768896;            // 26,624
  half_t* w2r  = w1r + 26624;               // 401,408
  half_t* w3r  = w2r + 401408;              // 819,200
  half_t* w4r  = w3r + 819200;              // 3,276,800
  half_t* w5r  = w4r + 3276800;             // 6,553,600
  half_t* wih0ch = w5r + 6553600;           // 1,048,576
  half_t* wcat0h = wih0ch + 1048576;        // 1,048,576
  half_t* wcat1h = wcat0h + 1048576;        // 2,097,152
  half_t* fw1h   = wcat1h + 2097152;        // 262,144
  half_t* xpad   = fw1h + 262144;           // union: xpad / partial buffers
  half_t* pbH = xpad;
  float* pbC = (float*)xpad;

  half_t* A1 = BUF1;                        // [131072 px][64]
  half_t* A2 = BUF2;                        // [21632][128]
  half_t* A3 = BUF1;                        // [10368][256]
  half_t* A4 = BUF2;                        // [3200][512]  (A2 dead)
  half_t* feat = BUF1;                      // [128][512]   (A3 dead)
  half_t* ys   = BUF2;                      // [2560][512]  (A4 dead post-conv5)
  half_t* fc1o = BUF2 + 1310720;

  dim3 blk(256);

  // ---- prep (single launch) ----
  prep_main<<<ELEM_BLOCKS + 1408, blk, 0, stream>>>(
      x, w1, w2, w3, w4, w5, wih0, whh0, bih0, bhh0, wih1, whh1, bih1, bhh1, fw1,
      bg0c, bg1c, c0, (unsigned*)h0a, xpad, w1r, w2r, w3r, w4r, w5r,
      wih0ch, fw1h, wcat0h, wcat1h);

  // ---- conv stack (round-11 proven: fp16/f32 partials + finalize launches) ----
  conv_mfma<7, 2, 3, 0><<<dim3(2048, 1, 1), blk, 0, stream>>>(
      xpad, w1r, b1, A1, 70, 70, 32, 32, 64, 416, 13, 0.2f, 0);
  conv_mfma128<7, 2, 6, 3><<<338, blk, 0, stream>>>(
      A1, w2r, b2, pbH, 32, 32, 13, 13, 128, 3136, 49, 0.2f, 2768896LL, 1, 2);
  finalize_h<<<1352, blk, 0, stream>>>(pbH, b2, A2, 346112, 2, 127, 2768896LL);
  conv_mfma128<5, 1, 7, 3><<<324, blk, 0, stream>>>(
      A2, w3r, b3, pbH, 13, 13, 9, 9, 256, 3200, 50, 0.2f, 2654208LL, 2, 4);
  finalize_h<<<1296, blk, 0, stream>>>(pbH, b3, A3, 331776, 2, 255, 2654208LL);
  conv_mfma128<5, 1, 8, 3><<<400, blk, 0, stream>>>(
      A3, w4r, b4, pbH, 9, 9, 5, 5, 512, 6400, 50, 0.2f, 1638400LL, 4, 16);
  finalize_h<<<800, blk, 0, stream>>>(pbH, b4, A4, 204800, 4, 511, 1638400LL);
  conv_mfma<5, 1, 9, 2><<<dim3(2, 8, 25), blk, 0, stream>>>(
      A4, w5r, b5, pbC, 5, 5, 1, 1, 512, 12800, 16, 0.2f, 65536LL);
  finalize_part<<<256, blk, 0, stream>>>(pbC, b5, feat, 65536, 25);

  // ---- LSTM step 1 (replaces xw0 GEMM + old launch 1) ----
  half_t* h0buf[2] = {h0a, h0b};
  half_t* h1buf[2] = {h1a, h1b};
  lstm0_step<<<dim3(2, 32), blk, 0, stream>>>(feat, wih0ch, bg0c, xw0c, c0, h0b);

  // ---- LSTM steps 2..20, fused l0(t)||l1(t-1)||fc1(chunk t-3) ----
  lstm_fused<<<dim3(2, 32, 2), blk, 0, stream>>>(
      h0buf[1], h0buf[0], h1buf[0], h1buf[1], wcat0h, wcat1h, xw0c, bg1c, c0, c1,
      ys, 1, -1, fw1h, fb1, nullptr, nullptr);
  for (int t = 3; t <= 20; ++t) {
    lstm_fused<<<dim3(2, 32, 3), blk, 0, stream>>>(
        h0buf[(t - 1) & 1], h0buf[t & 1], h1buf[t & 1], h1buf[(t - 1) & 1],
        wcat0h, wcat1h, xw0c, bg1c, c0, c1, ys + (size_t)(t - 2) * 65536,
        1, 2, fw1h, fb1, ys + (size_t)(t - 3) * 65536, fc1o + (size_t)(t - 3) * 65536);
  }
  lstm_fused<<<dim3(2, 32, 2), blk, 0, stream>>>(
      h0buf[0], h0buf[1], h1buf[1], h1buf[0],
      wcat0h, wcat1h, xw0c, bg1c, c0, c1, ys + (size_t)19 * 65536,
      0, 1, fw1h, fb1, ys + (size_t)18 * 65536, fc1o + (size_t)18 * 65536);

  // ---- FC head tail: fc1 chunk 19, then fc2 ----
  conv_mfma<1, 1, 9, 0><<<dim3(2, 8, 1), blk, 0, stream>>>(
      ys + (size_t)19 * 65536, fw1h, fb1, fc1o + (size_t)19 * 65536,
      1, 1, 1, 1, 512, 512, 16, 0.01f, 0);
  fc2_sigmoid<<<130, blk, 0, stream>>>(fc1o, fw2, fb2, out);
}

// Round 15
// 386.409 us; speedup vs baseline: 1.8103x; 1.0392x over previous
//
#include <hip/hip_runtime.h>
#include <math.h>

typedef _Float16 half_t;
typedef __attribute__((ext_vector_type(8))) _Float16 f16x8;
typedef __attribute__((ext_vector_type(4))) _Float16 f16x4;
typedef __attribute__((ext_vector_type(4))) float f32x4;

#define LEAKY(v, s) ((v) >= 0.f ? (v) : (s) * (v))

__device__ __forceinline__ float sig_(float x) { return 1.f / (1.f + expf(-x)); }
__device__ __forceinline__ half_t f2h(float f) { return (half_t)f; }

#define GLD(gp, lp)                                              \
  __builtin_amdgcn_global_load_lds(                              \
      (const __attribute__((address_space(1))) void*)(gp),       \
      (__attribute__((address_space(3))) void*)(lp), 16, 0, 0)

#define PHASE_WAIT(N)                                            \
  asm volatile("s_waitcnt vmcnt(" #N ")" ::: "memory");          \
  __builtin_amdgcn_s_barrier();                                  \
  __builtin_amdgcn_sched_barrier(0)

// ---------------- elementwise prep (no LDS -> full occupancy) ----------------
// bg0c/bg1c and wih0c use LSTM "cat" order: row r = u*4+g.
#define R0 2048LL      // bg0c
#define R1 4096LL      // bg1c
#define R2 135168LL    // c zero (131072 f32)
#define R3 266240LL    // h zero (131072 u32)
#define R4 5283840LL   // pad_x (5017600)
#define R5 5310464LL   // w1r (26624)
#define R6 6359040LL   // wih0c (1048576)
#define R7 6621184LL   // fw1h (262144)
#define R8 7669760LL   // wcat0 (1048576)
#define R9 9766912LL   // wcat1 end -> 38152 blocks

__global__ void prep_elem(
    const float* __restrict__ x, const float* __restrict__ w1,
    const float* __restrict__ wih0, const float* __restrict__ whh0,
    const float* __restrict__ bih0, const float* __restrict__ bhh0,
    const float* __restrict__ wih1, const float* __restrict__ whh1,
    const float* __restrict__ bih1, const float* __restrict__ bhh1,
    const float* __restrict__ fw1,
    float* __restrict__ bg0c, float* __restrict__ bg1c,
    float* __restrict__ czero, unsigned* __restrict__ hzero,
    half_t* __restrict__ xpad, half_t* __restrict__ w1r,
    half_t* __restrict__ wih0c, half_t* __restrict__ fw1h,
    half_t* __restrict__ wcat0h, half_t* __restrict__ wcat1h) {
  long long i = (long long)blockIdx.x * blockDim.x + threadIdx.x;
  if (i < R0) {
    int j = (int)i;
    int u = j >> 2, g = j & 3;
    bg0c[j] = bih0[g * 512 + u] + bhh0[g * 512 + u];
  } else if (i < R1) {
    int j = (int)(i - R0);
    int u = j >> 2, g = j & 3;
    bg1c[j] = bih1[g * 512 + u] + bhh1[g * 512 + u];
  } else if (i < R2) {
    czero[i - R1] = 0.f;
  } else if (i < R3) {
    hzero[i - R2] = 0u;
  } else if (i < R4) {
    long long j = i - R3;
    int c = j & 7;
    long long t = j >> 3;
    int iw = t % 70; t /= 70;
    int ih = t % 70;
    int n = t / 70;
    float v = 0.f;
    if (c < 3 && ih >= 3 && ih < 67 && iw >= 3 && iw < 67)
      v = x[((n * 3 + c) * 64 + (ih - 3)) * 64 + (iw - 3)];
    xpad[j] = f2h(v);
  } else if (i < R5) {
    int j = (int)(i - R4);
    int kg = j % 416, co = j / 416;
    int ci = kg & 7, tap = kg >> 3;
    float v = 0.f;
    if (tap < 49 && ci < 3) {
      int kh = tap / 7, kw = tap % 7;
      v = w1[((co * 3 + ci) * 7 + kh) * 7 + kw];
    }
    w1r[j] = f2h(v);
  } else if (i < R6) {
    int j = (int)(i - R5);
    int r = j >> 9, k = j & 511;
    int u = r >> 2, g = r & 3;
    wih0c[j] = f2h(wih0[(g * 512 + u) * 512 + k]);
  } else if (i < R7) {
    int j = (int)(i - R6);
    fw1h[j] = f2h(fw1[j]);
  } else if (i < R8) {
    int j = (int)(i - R7);
    int r = j >> 9, k = j & 511;
    int u = r >> 2, g = r & 3;
    wcat0h[j] = f2h(whh0[(g * 512 + u) * 512 + k]);
  } else if (i < R9) {
    int j = (int)(i - R8);
    int r = j >> 10, k = j & 1023;
    int u = r >> 2, g = r & 3;
    int row = g * 512 + u;
    wcat1h[j] = f2h(k < 512 ? wih1[row * 512 + k] : whh1[row * 512 + (k - 512)]);
  }
}

// ---------------- LDS-bounce weight transpose (coalesced both ways) ----------------
__global__ __launch_bounds__(256) void prep_wT(
    const float* __restrict__ w2, const float* __restrict__ w3,
    const float* __restrict__ w4, const float* __restrict__ w5,
    half_t* __restrict__ w2r, half_t* __restrict__ w3r,
    half_t* __restrict__ w4r, half_t* __restrict__ w5r) {
  __shared__ float T[12800];
  int bid = blockIdx.x, tid = threadIdx.x;
  const float* W;
  half_t* D;
  int co, Cin, TAP, lg2;
  if (bid < 128) {
    W = w2; D = w2r; co = bid; Cin = 64; TAP = 49; lg2 = 6;
  } else if (bid < 384) {
    W = w3; D = w3r; co = bid - 128; Cin = 128; TAP = 25; lg2 = 7;
  } else if (bid < 896) {
    W = w4; D = w4r; co = bid - 384; Cin = 256; TAP = 25; lg2 = 8;
  } else {
    W = w5; D = w5r; co = bid - 896; Cin = 512; TAP = 25; lg2 = 9;
  }
  int n = Cin * TAP;
  const float* src = W + (size_t)co * n;
  for (int i = tid; i < n; i += 256) T[i] = src[i];
  __syncthreads();
  half_t* dst = D + (size_t)co * n;
  for (int j = tid; j < n; j += 256) {
    int ci = j & (Cin - 1);
    int tap = j >> lg2;
    dst[j] = f2h(T[ci * TAP + tap]);
  }
}

// ---------------- 64x64 fp16 MFMA conv / GEMM ----------------
// OUTMODE: 0 fp16+bias+leaky; 2 f32 raw partial at z*zstride.
template <int KW, int S, int LOG2CIN, int OUTMODE>
__global__ __launch_bounds__(256) void conv_mfma(
    const half_t* __restrict__ xin, const half_t* __restrict__ wr,
    const float* __restrict__ bias, void* __restrict__ outp,
    int Hin, int Win, int Hout, int Wout, int Cout, int K, int ktiles, float slope,
    long long zstride) {
  constexpr int CIN = 1 << LOG2CIN;
  __shared__ half_t lds[4][4096];
  const int tid = threadIdx.x;
  const int lane = tid & 63, wid = tid >> 6;
  const int sRow = tid >> 2, sCh = tid & 3;
  const int sSwz = sCh ^ ((sRow ^ (sRow >> 2)) & 3);
  const int kt0 = blockIdx.z * ktiles;
  const half_t* gArow = wr + (size_t)(blockIdx.y * 64 + sRow) * K + sSwz * 8;
  int p = blockIdx.x * 64 + sRow;
  int hw = Hout * Wout;
  int n = p / hw;
  int rem = p - n * hw;
  int oh = rem / Wout;
  int ow = rem - oh * Wout;
  const half_t* xb = xin + ((size_t)(n * Hin + oh * S) * Win + ow * S) * CIN;
  const int fr = lane & 15, fc = lane >> 4;
  const int r0 = (wid & 1) * 32, c0 = (wid >> 1) * 32;
  const int sw = (fc ^ ((fr ^ (fr >> 2)) & 3)) * 8;
  const int ia0 = (r0 + fr) * 32 + sw;
  const int ia1 = (r0 + 16 + fr) * 32 + sw;
  const int ib0 = 2048 + (c0 + fr) * 32 + sw;
  const int ib1 = 2048 + (c0 + 16 + fr) * 32 + sw;

  auto stage = [&](int t, int buf) {
    GLD(gArow + (size_t)(kt0 + t) * 32, &lds[buf][wid * 512]);
    int kg = (kt0 + t) * 32 + sSwz * 8;
    int ci = kg & (CIN - 1);
    int tap = kg >> LOG2CIN;
    int kh = tap / KW, kw = tap - kh * KW;
    GLD(xb + (kh * Win + kw) * CIN + ci, &lds[buf][2048 + wid * 512]);
  };

  f32x4 acc00 = {0.f, 0.f, 0.f, 0.f};
  f32x4 acc01 = acc00, acc10 = acc00, acc11 = acc00;

  auto compute = [&](int buf) {
    const half_t* L = &lds[buf][0];
    f16x8 a0 = *(const f16x8*)&L[ia0];
    f16x8 a1 = *(const f16x8*)&L[ia1];
    f16x8 b0 = *(const f16x8*)&L[ib0];
    f16x8 b1 = *(const f16x8*)&L[ib1];
    acc00 = __builtin_amdgcn_mfma_f32_16x16x32_f16(a0, b0, acc00, 0, 0, 0);
    acc01 = __builtin_amdgcn_mfma_f32_16x16x32_f16(a0, b1, acc01, 0, 0, 0);
    acc10 = __builtin_amdgcn_mfma_f32_16x16x32_f16(a1, b0, acc10, 0, 0, 0);
    acc11 = __builtin_amdgcn_mfma_f32_16x16x32_f16(a1, b1, acc11, 0, 0, 0);
  };

  stage(0, 0);
  stage(1, 1);
  stage(2, 2);
  int t = 0;
  for (; t < ktiles - 3; ++t) {
    PHASE_WAIT(4);
    stage(t + 3, (t + 3) & 3);
    compute(t & 3);
  }
  PHASE_WAIT(4);
  compute(t & 3);
  ++t;
  PHASE_WAIT(2);
  compute(t & 3);
  ++t;
  PHASE_WAIT(0);
  compute(t & 3);

#pragma unroll
  for (int am = 0; am < 2; ++am) {
#pragma unroll
    for (int bn = 0; bn < 2; ++bn) {
      f32x4 a = am == 0 ? (bn == 0 ? acc00 : acc01) : (bn == 0 ? acc10 : acc11);
      int co = blockIdx.y * 64 + r0 + am * 16 + fc * 4;
      int px = blockIdx.x * 64 + c0 + bn * 16 + fr;
      size_t o = (size_t)px * Cout + co;
      if (OUTMODE == 2) {
        float* pb = (float*)outp + (size_t)blockIdx.z * zstride;
        *(f32x4*)&pb[o] = a;
      } else {
        f32x4 bb = *(const f32x4*)&bias[co];
        f16x4 hv;
#pragma unroll
        for (int j = 0; j < 4; ++j) {
          float tt = a[j] + bb[j];
          hv[j] = f2h(LEAKY(tt, slope));
        }
        *(f16x4*)&((half_t*)outp)[o] = hv;
      }
    }
  }
}

// ---------------- 128x128 fp16 MFMA conv, XCD-swizzled 1D grid ----------------
// OUTMODE: 0 fp16+bias+leaky; 3 fp16 raw partial at bz*zstride.
template <int KW, int S, int LOG2CIN, int OUTMODE>
__global__ __launch_bounds__(256) void conv_mfma128(
    const half_t* __restrict__ xin, const half_t* __restrict__ wr,
    const float* __restrict__ bias, void* __restrict__ outp,
    int Hin, int Win, int Hout, int Wout, int Cout, int K, int ktiles, float slope,
    long long zstride, int Y, int G) {
  constexpr int CIN = 1 << LOG2CIN;
  __shared__ half_t lds[4][8192];
  const int L = blockIdx.x;
  const int bx = L / G;
  const int g = L % G;
  const int by = g % Y;
  const int bz = g / Y;
  const int tid = threadIdx.x;
  const int lane = tid & 63, wid = tid >> 6;
  const int sRow = tid >> 2, sCh = tid & 3;
  const int sSwz = sCh ^ ((sRow ^ (sRow >> 2)) & 3);
  const int kt0 = bz * ktiles;
  const half_t* gA0 = wr + (size_t)(by * 128 + sRow) * K + sSwz * 8;
  const half_t* gA1 = wr + (size_t)(by * 128 + 64 + sRow) * K + sSwz * 8;
  int hw = Hout * Wout;
  int p0 = bx * 128 + sRow;
  int n0 = p0 / hw, r0p = p0 - n0 * hw, oh0 = r0p / Wout, ow0 = r0p - oh0 * Wout;
  const half_t* xb0 = xin + ((size_t)(n0 * Hin + oh0 * S) * Win + ow0 * S) * CIN;
  int p1 = p0 + 64;
  int n1 = p1 / hw, r1p = p1 - n1 * hw, oh1 = r1p / Wout, ow1 = r1p - oh1 * Wout;
  const half_t* xb1 = xin + ((size_t)(n1 * Hin + oh1 * S) * Win + ow1 * S) * CIN;

  const int fr = lane & 15, fc = lane >> 4;
  const int wr_ = wid & 1, wc_ = wid >> 1;
  const int sw = (fc ^ ((fr ^ (fr >> 2)) & 3)) * 8;
  const int iaB = (wr_ * 64 + fr) * 32 + sw;
  const int ibB = 4096 + (wc_ * 64 + fr) * 32 + sw;

  auto stage = [&](int t, int buf) {
    half_t* LB = &lds[buf][0];
    GLD(gA0 + (size_t)(kt0 + t) * 32, LB + wid * 512);
    GLD(gA1 + (size_t)(kt0 + t) * 32, LB + 2048 + wid * 512);
    int kg = (kt0 + t) * 32 + sSwz * 8;
    int ci = kg & (CIN - 1);
    int tap = kg >> LOG2CIN;
    int kh = tap / KW, kw = tap - kh * KW;
    int xoff = (kh * Win + kw) * CIN + ci;
    GLD(xb0 + xoff, LB + 4096 + wid * 512);
    GLD(xb1 + xoff, LB + 6144 + wid * 512);
  };

  f32x4 acc[4][4];
#pragma unroll
  for (int i = 0; i < 4; ++i)
#pragma unroll
    for (int j = 0; j < 4; ++j) acc[i][j] = (f32x4){0.f, 0.f, 0.f, 0.f};

  auto compute = [&](int buf) {
    const half_t* L2 = &lds[buf][0];
    f16x8 a[4], b[4];
#pragma unroll
    for (int fi = 0; fi < 4; ++fi) a[fi] = *(const f16x8*)&L2[iaB + fi * 512];
#pragma unroll
    for (int fj = 0; fj < 4; ++fj) b[fj] = *(const f16x8*)&L2[ibB + fj * 512];
#pragma unroll
    for (int fi = 0; fi < 4; ++fi)
#pragma unroll
      for (int fj = 0; fj < 4; ++fj)
        acc[fi][fj] = __builtin_amdgcn_mfma_f32_16x16x32_f16(a[fi], b[fj], acc[fi][fj], 0, 0, 0);
  };

  stage(0, 0);
  stage(1, 1);
  stage(2, 2);
  int t = 0;
  for (; t < ktiles - 3; ++t) {
    PHASE_WAIT(8);
    stage(t + 3, (t + 3) & 3);
    compute(t & 3);
  }
  PHASE_WAIT(8);
  compute(t & 3);
  ++t;
  PHASE_WAIT(4);
  compute(t & 3);
  ++t;
  PHASE_WAIT(0);
  compute(t & 3);

#pragma unroll
  for (int fi = 0; fi < 4; ++fi) {
#pragma unroll
    for (int fj = 0; fj < 4; ++fj) {
      int co = by * 128 + wr_ * 64 + fi * 16 + fc * 4;
      int px = bx * 128 + wc_ * 64 + fj * 16 + fr;
      size_t o = (size_t)px * Cout + co;
      if (OUTMODE == 3) {
        half_t* pb = (half_t*)outp + (size_t)bz * zstride;
        f16x4 hv;
#pragma unroll
        for (int j = 0; j < 4; ++j) hv[j] = f2h(acc[fi][fj][j]);
        *(f16x4*)&pb[o] = hv;
      } else {
        f32x4 bb = *(const f32x4*)&bias[co];
        f16x4 hv;
#pragma unroll
        for (int j = 0; j < 4; ++j) {
          float tt = acc[fi][fj][j] + bb[j];
          hv[j] = f2h(LEAKY(tt, slope));
        }
        *(f16x4*)&((half_t*)outp)[o] = hv;
      }
    }
  }
}

// reduce K-split f32 partials (conv5)
__global__ void finalize_part(const float* __restrict__ pb, const float* __restrict__ bias,
                              half_t* __restrict__ out, int size, int nz) {
  int i = blockIdx.x * blockDim.x + threadIdx.x;
  if (i >= size) return;
  float s = bias[i & 511];
  for (int z = 0; z < nz; ++z) s += pb[(size_t)z * size + i];
  out[i] = f2h(LEAKY(s, 0.2f));
}

// reduce fp16 K-split partials, vectorized x8
__global__ void finalize_h(const half_t* __restrict__ pb, const float* __restrict__ bias,
                           half_t* __restrict__ out, int size8, int nz, int cmask,
                           long long zstride) {
  int idx = blockIdx.x * blockDim.x + threadIdx.x;
  if (idx >= size8) return;
  long long i = (long long)idx * 8;
  float s[8];
#pragma unroll
  for (int q = 0; q < 8; ++q) s[q] = bias[(int)((i + q) & cmask)];
  for (int z = 0; z < nz; ++z) {
    f16x8 v = *(const f16x8*)&pb[(size_t)z * zstride + i];
#pragma unroll
    for (int q = 0; q < 8; ++q) s[q] += (float)v[q];
  }
  f16x8 o;
#pragma unroll
  for (int q = 0; q < 8; ++q) o[q] = f2h(LEAKY(s[q], 0.2f));
  *(f16x8*)&out[i] = o;
}

// ---------------- LSTM step 1: xw0c = feat@wih0c^T + bg0c, gates -> h0_1, c0 ----
__global__ __launch_bounds__(256) void lstm0_step(
    const half_t* __restrict__ feat, const half_t* __restrict__ wih0c,
    const float* __restrict__ bg0c, float* __restrict__ xw0c,
    float* __restrict__ c0, half_t* __restrict__ h0out) {
  __shared__ half_t lds[4][8192];
  const int tid = threadIdx.x;
  const int lane = tid & 63, wid = tid >> 6;
  const int ybase = blockIdx.y * 64, bbase = blockIdx.x * 64;
  const int rA0 = wid * 16 + (lane >> 3);
  const int rA1 = rA0 + 8;
  const int chS = ((lane & 7) ^ ((lane >> 3) & 7)) * 8;
  const half_t* gA0 = wih0c + (size_t)(ybase + rA0) * 512 + chS;
  const half_t* gA1 = wih0c + (size_t)(ybase + rA1) * 512 + chS;
  const size_t hb0 = (size_t)(bbase + rA0) * 512 + chS;
  const size_t hb1 = (size_t)(bbase + rA1) * 512 + chS;

  auto stage = [&](int t, int buf) {
    GLD(gA0 + t * 64, &lds[buf][wid * 1024]);
    GLD(gA1 + t * 64, &lds[buf][wid * 1024 + 512]);
    GLD(feat + hb0 + t * 64, &lds[buf][4096 + wid * 1024]);
    GLD(feat + hb1 + t * 64, &lds[buf][4096 + wid * 1024 + 512]);
  };

  const int fr = lane & 15, fc = lane >> 4;
  const int wr_ = wid & 1, wc_ = wid >> 1;

  f32x4 acc[2][2];
#pragma unroll
  for (int fi = 0; fi < 2; ++fi)
#pragma unroll
    for (int fj = 0; fj < 2; ++fj) acc[fi][fj] = (f32x4){0.f, 0.f, 0.f, 0.f};

  auto compute = [&](int buf) {
    const half_t* L = &lds[buf][0];
#pragma unroll
    for (int s = 0; s < 2; ++s) {
      f16x8 a[2], b[2];
#pragma unroll
      for (int fi = 0; fi < 2; ++fi) {
        int row = wr_ * 32 + fi * 16 + fr;
        a[fi] = *(const f16x8*)&L[row * 64 + (((s * 4 + fc) ^ (fr & 7)) * 8)];
      }
#pragma unroll
      for (int fj = 0; fj < 2; ++fj) {
        int brow = wc_ * 32 + fj * 16 + fr;
        b[fj] = *(const f16x8*)&L[4096 + brow * 64 + (((s * 4 + fc) ^ (fr & 7)) * 8)];
      }
#pragma unroll
      for (int fi = 0; fi < 2; ++fi)
#pragma unroll
        for (int fj = 0; fj < 2; ++fj)
          acc[fi][fj] = __builtin_amdgcn_mfma_f32_16x16x32_f16(a[fi], b[fj], acc[fi][fj], 0, 0, 0);
    }
  };

  stage(0, 0);
  stage(1, 1);
  stage(2, 2);
  int t = 0;
  for (; t < 5; ++t) {
    PHASE_WAIT(8);
    stage(t + 3, (t + 3) & 3);
    compute(t & 3);
  }
  PHASE_WAIT(8);
  compute(5 & 3);
  PHASE_WAIT(4);
  compute(6 & 3);
  PHASE_WAIT(0);
  compute(7 & 3);

#pragma unroll
  for (int fi = 0; fi < 2; ++fi) {
#pragma unroll
    for (int fj = 0; fj < 2; ++fj) {
      int Rb = ybase + wr_ * 32 + fi * 16 + fc * 4;  // row = u*4+g, gate = j
      int u = Rb >> 2;
      int b = bbase + wc_ * 32 + fj * 16 + fr;
      f32x4 bb = *(const f32x4*)&bg0c[Rb];
      f32x4 pre;
#pragma unroll
      for (int j = 0; j < 4; ++j) pre[j] = acc[fi][fj][j] + bb[j];
      *(f32x4*)&xw0c[(size_t)b * 2048 + Rb] = pre;
      float ig = sig_(pre[0]);
      float gg = tanhf(pre[2]);
      float og = sig_(pre[3]);
      float cn = ig * gg;  // c_prev = 0
      float hn = og * tanhf(cn);
      int ci = b * 512 + u;
      c0[ci] = cn;
      h0out[ci] = f2h(hn);
    }
  }
}

// ---------------- fused LSTM step + optional fc1 plane ----------------
__global__ __launch_bounds__(256) void lstm_fused(
    const half_t* __restrict__ h0in, half_t* __restrict__ h0out,
    const half_t* __restrict__ h1in, half_t* __restrict__ h1out,
    const half_t* __restrict__ wcat0, const half_t* __restrict__ wcat1,
    const float* __restrict__ xw0c, const float* __restrict__ bg1c,
    float* __restrict__ c0, float* __restrict__ c1,
    half_t* __restrict__ ysout, int zl1, int zfc,
    const half_t* __restrict__ fcw, const float* __restrict__ fcb,
    const half_t* __restrict__ fcin, half_t* __restrict__ fcout) {
  const int bzp = blockIdx.z;
  const bool isFC = (bzp == zfc);
  const bool isL1 = (bzp == zl1);
  if (isFC && blockIdx.y >= 8) return;
  const int NT = isL1 ? 16 : 8;
  const half_t* Asrc = isFC ? fcw : (isL1 ? wcat1 : wcat0);
  const int K = NT * 64;

  __shared__ half_t lds[4][8192];
  const int tid = threadIdx.x;
  const int lane = tid & 63, wid = tid >> 6;
  const int ybase = blockIdx.y * 64, bbase = blockIdx.x * 64;
  const int rA0 = wid * 16 + (lane >> 3);
  const int rA1 = rA0 + 8;
  const int chS = ((lane & 7) ^ ((lane >> 3) & 7)) * 8;
  const half_t* gA0 = Asrc + (size_t)(ybase + rA0) * K + chS;
  const half_t* gA1 = Asrc + (size_t)(ybase + rA1) * K + chS;
  const size_t hb0 = (size_t)(bbase + rA0) * 512 + chS;
  const size_t hb1 = (size_t)(bbase + rA1) * 512 + chS;
  const half_t* bsrc0 = isFC ? fcin : h0in;

  auto stage = [&](int t, int buf) {
    GLD(gA0 + t * 64, &lds[buf][wid * 1024]);
    GLD(gA1 + t * 64, &lds[buf][wid * 1024 + 512]);
    const half_t* hs = (isL1 && t >= 8) ? h1in : bsrc0;
    int koff = (isL1 && t >= 8) ? (t - 8) * 64 : t * 64;
    GLD(hs + hb0 + koff, &lds[buf][4096 + wid * 1024]);
    GLD(hs + hb1 + koff, &lds[buf][4096 + wid * 1024 + 512]);
  };

  const int fr = lane & 15, fc = lane >> 4;
  const int wr_ = wid & 1, wc_ = wid >> 1;

  f32x4 acc[2][2];
#pragma unroll
  for (int fi = 0; fi < 2; ++fi)
#pragma unroll
    for (int fj = 0; fj < 2; ++fj) acc[fi][fj] = (f32x4){0.f, 0.f, 0.f, 0.f};

  auto compute = [&](int buf) {
    const half_t* L = &lds[buf][0];
#pragma unroll
    for (int s = 0; s < 2; ++s) {
      f16x8 a[2], b[2];
#pragma unroll
      for (int fi = 0; fi < 2; ++fi) {
        int row = wr_ * 32 + fi * 16 + fr;
        a[fi] = *(const f16x8*)&L[row * 64 + (((s * 4 + fc) ^ (fr & 7)) * 8)];
      }
#pragma unroll
      for (int fj = 0; fj < 2; ++fj) {
        int brow = wc_ * 32 + fj * 16 + fr;
        b[fj] = *(const f16x8*)&L[4096 + brow * 64 + (((s * 4 + fc) ^ (fr & 7)) * 8)];
      }
#pragma unroll
      for (int fi = 0; fi < 2; ++fi)
#pragma unroll
        for (int fj = 0; fj < 2; ++fj)
          acc[fi][fj] = __builtin_amdgcn_mfma_f32_16x16x32_f16(a[fi], b[fj], acc[fi][fj], 0, 0, 0);
    }
  };

  stage(0, 0);
  stage(1, 1);
  stage(2, 2);
  int t = 0;
  for (; t < NT - 3; ++t) {
    PHASE_WAIT(8);
    stage(t + 3, (t + 3) & 3);
    compute(t & 3);
  }
  PHASE_WAIT(8);
  compute(t & 3);
  ++t;
  PHASE_WAIT(4);
  compute(t & 3);
  ++t;
  PHASE_WAIT(0);
  compute(t & 3);

  if (isFC) {
#pragma unroll
    for (int fi = 0; fi < 2; ++fi) {
#pragma unroll
      for (int fj = 0; fj < 2; ++fj) {
        int Rb = ybase + wr_ * 32 + fi * 16 + fc * 4;  // co base
        int b = bbase + wc_ * 32 + fj * 16 + fr;       // chunk-local row
        f32x4 bb = *(const f32x4*)&fcb[Rb];
        f16x4 hv;
#pragma unroll
        for (int j = 0; j < 4; ++j) {
          float tt = acc[fi][fj][j] + bb[j];
          hv[j] = f2h(LEAKY(tt, 0.01f));
        }
        *(f16x4*)&fcout[(size_t)b * 512 + Rb] = hv;
      }
    }
    return;
  }

  float* c = isL1 ? c1 : c0;
  half_t* hout = isL1 ? h1out : h0out;
#pragma unroll
  for (int fi = 0; fi < 2; ++fi) {
#pragma unroll
    for (int fj = 0; fj < 2; ++fj) {
      int Rb = ybase + wr_ * 32 + fi * 16 + fc * 4;  // row = u*4+g, gate = j
      int u = Rb >> 2;
      int b = bbase + wc_ * 32 + fj * 16 + fr;
      f32x4 bb = isL1 ? *(const f32x4*)&bg1c[Rb]
                      : *(const f32x4*)&xw0c[(size_t)b * 2048 + Rb];
      float p[4];
#pragma unroll
      for (int j = 0; j < 4; ++j) p[j] = acc[fi][fj][j] + bb[j];
      int ci = b * 512 + u;
      float cprev = c[ci];
      float ig = sig_(p[0]);
      float fg = sig_(p[1]);
      float gg = tanhf(p[2]);
      float og = sig_(p[3]);
      float cn = fg * cprev + ig * gg;
      float hn = og * tanhf(cn);
      c[ci] = cn;
      hout[ci] = f2h(hn);
      if (isL1) ysout[ci] = f2h(hn);
    }
  }
}

// ---------------- final FC: sigmoid(fc1o @ fw2.T + fb2), [2560,13] ----------------
__global__ void fc2_sigmoid(const half_t* __restrict__ in, const float* __restrict__ w,
                            const float* __restrict__ b, float* __restrict__ out) {
  int idx = blockIdx.x * blockDim.x + threadIdx.x;
  if (idx >= 2560 * 13) return;
  int j = idx % 13, r = idx / 13;
  const half_t* ip = in + (size_t)r * 512;
  const float* wp = w + j * 512;
  float s = b[j];
  for (int k = 0; k < 512; k += 8) {
    f16x8 hv = *(const f16x8*)&ip[k];
#pragma unroll
    for (int q = 0; q < 8; ++q) s = fmaf((float)hv[q], wp[k + q], s);
  }
  out[idx] = sig_(s);
}

// ---------------- launch ----------------
extern "C" void kernel_launch(void* const* d_in, const int* in_sizes, int n_in,
                              void* d_out, int out_size, void* d_ws, size_t ws_size,
                              hipStream_t stream) {
  const float* x   = (const float*)d_in[0];
  const float* w1  = (const float*)d_in[1];  const float* b1 = (const float*)d_in[2];
  const float* w2  = (const float*)d_in[3];  const float* b2 = (const float*)d_in[4];
  const float* w3  = (const float*)d_in[5];  const float* b3 = (const float*)d_in[6];
  const float* w4  = (const float*)d_in[7];  const float* b4 = (const float*)d_in[8];
  const float* w5  = (const float*)d_in[9];  const float* b5 = (const float*)d_in[10];
  const float* wih0 = (const float*)d_in[11]; const float* whh0 = (const float*)d_in[12];
  const float* bih0 = (const float*)d_in[13]; const float* bhh0 = (const float*)d_in[14];
  const float* wih1 = (const float*)d_in[15]; const float* whh1 = (const float*)d_in[16];
  const float* bih1 = (const float*)d_in[17]; const float* bhh1 = (const float*)d_in[18];
  const float* fw1 = (const float*)d_in[19]; const float* fb1 = (const float*)d_in[20];
  const float* fw2 = (const float*)d_in[21]; const float* fb2 = (const float*)d_in[22];
  float* out = (float*)d_out;

  // ---- workspace layout (within 75.6 MB proven) ----
  float* bg0c = (float*)d_ws;               // 2048
  float* bg1c = bg0c + 2048;                // 2048
  float* xw0c = bg1c + 2048;                // 262144
  float* c0  = xw0c + 262144;               // 65536
  float* c1  = c0 + 65536;                  // 65536
  half_t* h0a = (half_t*)(c1 + 65536);      // 4 x 65536 halves
  half_t* h0b = h0a + 65536;
  half_t* h1a = h0b + 65536;
  half_t* h1b = h1a + 65536;
  half_t* BUF1 = h1b + 65536;               // 8,388,608  [A1 -> A3 -> feat]
  half_t* BUF2 = BUF1 + 8388608;            // 2,768,896  [A2 -> A4 -> ys+fc1o]
  half_t* w1r  = BUF2 + 2768896;            // 26,624
  half_t* w2r  = w1r + 26624;               // 401,408
  half_t* w3r  = w2r + 401408;              // 819,200
  half_t* w4r  = w3r + 819200;              // 3,276,800
  half_t* w5r  = w4r + 3276800;             // 6,553,600
  half_t* wih0ch = w5r + 6553600;           // 1,048,576
  half_t* wcat0h = wih0ch + 1048576;        // 1,048,576
  half_t* wcat1h = wcat0h + 1048576;        // 2,097,152
  half_t* fw1h   = wcat1h + 2097152;        // 262,144
  half_t* xpad   = fw1h + 262144;           // union: xpad / partial buffers
  half_t* pbH = xpad;
  float* pbC = (float*)xpad;

  half_t* A1 = BUF1;                        // [131072 px][64]
  half_t* A2 = BUF2;                        // [21632][128]
  half_t* A3 = BUF1;                        // [10368][256]
  half_t* A4 = BUF2;                        // [3200][512]  (A2 dead)
  half_t* feat = BUF1;                      // [128][512]   (A3 dead)
  half_t* ys   = BUF2;                      // [2560][512]  (A4 dead post-conv5)
  half_t* fc1o = BUF2 + 1310720;

  dim3 blk(256);

  // ---- prep: elementwise (no LDS, full occupancy) + LDS-bounce transposes ----
  prep_elem<<<38152, blk, 0, stream>>>(
      x, w1, wih0, whh0, bih0, bhh0, wih1, whh1, bih1, bhh1, fw1,
      bg0c, bg1c, c0, (unsigned*)h0a, xpad, w1r, wih0ch, fw1h, wcat0h, wcat1h);
  prep_wT<<<1408, blk, 0, stream>>>(w2, w3, w4, w5, w2r, w3r, w4r, w5r);

  // ---- conv stack ----
  conv_mfma<7, 2, 3, 0><<<dim3(2048, 1, 1), blk, 0, stream>>>(
      xpad, w1r, b1, A1, 70, 70, 32, 32, 64, 416, 13, 0.2f, 0);
  conv_mfma128<7, 2, 6, 3><<<338, blk, 0, stream>>>(
      A1, w2r, b2, pbH, 32, 32, 13, 13, 128, 3136, 49, 0.2f, 2768896LL, 1, 2);
  finalize_h<<<1352, blk, 0, stream>>>(pbH, b2, A2, 346112, 2, 127, 2768896LL);
  conv_mfma128<5, 1, 7, 3><<<324, blk, 0, stream>>>(
      A2, w3r, b3, pbH, 13, 13, 9, 9, 256, 3200, 50, 0.2f, 2654208LL, 2, 4);
  finalize_h<<<1296, blk, 0, stream>>>(pbH, b3, A3, 331776, 2, 255, 2654208LL);
  conv_mfma128<5, 1, 8, 3><<<400, blk, 0, stream>>>(
      A3, w4r, b4, pbH, 9, 9, 5, 5, 512, 6400, 50, 0.2f, 1638400LL, 4, 16);
  finalize_h<<<800, blk, 0, stream>>>(pbH, b4, A4, 204800, 4, 511, 1638400LL);
  conv_mfma<5, 1, 9, 2><<<dim3(2, 8, 25), blk, 0, stream>>>(
      A4, w5r, b5, pbC, 5, 5, 1, 1, 512, 12800, 16, 0.2f, 65536LL);
  finalize_part<<<256, blk, 0, stream>>>(pbC, b5, feat, 65536, 25);

  // ---- LSTM step 1 (fused xw0 GEMM + gates) ----
  half_t* h0buf[2] = {h0a, h0b};
  half_t* h1buf[2] = {h1a, h1b};
  lstm0_step<<<dim3(2, 32), blk, 0, stream>>>(feat, wih0ch, bg0c, xw0c, c0, h0b);

  // ---- LSTM steps 2..20, fused l0(t)||l1(t-1)||fc1(chunk t-3) ----
  lstm_fused<<<dim3(2, 32, 2), blk, 0, stream>>>(
      h0buf[1], h0buf[0], h1buf[0], h1buf[1], wcat0h, wcat1h, xw0c, bg1c, c0, c1,
      ys, 1, -1, fw1h, fb1, nullptr, nullptr);
  for (int t = 3; t <= 20; ++t) {
    lstm_fused<<<dim3(2, 32, 3), blk, 0, stream>>>(
        h0buf[(t - 1) & 1], h0buf[t & 1], h1buf[t & 1], h1buf[(t - 1) & 1],
        wcat0h, wcat1h, xw0c, bg1c, c0, c1, ys + (size_t)(t - 2) * 65536,
        1, 2, fw1h, fb1, ys + (size_t)(t - 3) * 65536, fc1o + (size_t)(t - 3) * 65536);
  }
  lstm_fused<<<dim3(2, 32, 2), blk, 0, stream>>>(
      h0buf[0], h0buf[1], h1buf[1], h1buf[0],
      wcat0h, wcat1h, xw0c, bg1c, c0, c1, ys + (size_t)19 * 65536,
      0, 1, fw1h, fb1, ys + (size_t)18 * 65536, fc1o + (size_t)18 * 65536);

  // ---- FC head tail: fc1 chunk 19, then fc2 ----
  conv_mfma<1, 1, 9, 0><<<dim3(2, 8, 1), blk, 0, stream>>>(
      ys + (size_t)19 * 65536, fw1h, fb1, fc1o + (size_t)19 * 65536,
      1, 1, 1, 1, 512, 512, 16, 0.01f, 0);
  fc2_sigmoid<<<130, blk, 0, stream>>>(fc1o, fw2, fb2, out);
}

// Round 16
// 384.159 us; speedup vs baseline: 1.8209x; 1.0059x over previous
//
#include <hip/hip_runtime.h>
#include <math.h>

typedef _Float16 half_t;
typedef __attribute__((ext_vector_type(8))) _Float16 f16x8;
typedef __attribute__((ext_vector_type(4))) _Float16 f16x4;
typedef __attribute__((ext_vector_type(4))) float f32x4;

#define LEAKY(v, s) ((v) >= 0.f ? (v) : (s) * (v))

__device__ __forceinline__ float sig_(float x) { return 1.f / (1.f + expf(-x)); }
__device__ __forceinline__ half_t f2h(float f) { return (half_t)f; }

#define GLD(gp, lp)                                              \
  __builtin_amdgcn_global_load_lds(                              \
      (const __attribute__((address_space(1))) void*)(gp),       \
      (__attribute__((address_space(3))) void*)(lp), 16, 0, 0)

#define PHASE_WAIT(N)                                            \
  asm volatile("s_waitcnt vmcnt(" #N ")" ::: "memory");          \
  __builtin_amdgcn_s_barrier();                                  \
  __builtin_amdgcn_sched_barrier(0)

// ---------------- elementwise prep (no LDS -> full occupancy) ----------------
// bg0c/bg1c and wih0c use LSTM "cat" order: row r = u*4+g.
#define R0 2048LL      // bg0c
#define R1 4096LL      // bg1c
#define R2 135168LL    // c zero (131072 f32)
#define R3 266240LL    // h zero (131072 u32)
#define R4 5283840LL   // pad_x (5017600)
#define R5 5310464LL   // w1r (26624)
#define R6 6359040LL   // wih0c (1048576)
#define R7 6621184LL   // fw1h (262144)
#define R8 7669760LL   // wcat0 (1048576)
#define R9 9766912LL   // wcat1 end -> 38152 blocks

__global__ void prep_elem(
    const float* __restrict__ x, const float* __restrict__ w1,
    const float* __restrict__ wih0, const float* __restrict__ whh0,
    const float* __restrict__ bih0, const float* __restrict__ bhh0,
    const float* __restrict__ wih1, const float* __restrict__ whh1,
    const float* __restrict__ bih1, const float* __restrict__ bhh1,
    const float* __restrict__ fw1,
    float* __restrict__ bg0c, float* __restrict__ bg1c,
    float* __restrict__ czero, unsigned* __restrict__ hzero,
    half_t* __restrict__ xpad, half_t* __restrict__ w1r,
    half_t* __restrict__ wih0c, half_t* __restrict__ fw1h,
    half_t* __restrict__ wcat0h, half_t* __restrict__ wcat1h) {
  long long i = (long long)blockIdx.x * blockDim.x + threadIdx.x;
  if (i < R0) {
    int j = (int)i;
    int u = j >> 2, g = j & 3;
    bg0c[j] = bih0[g * 512 + u] + bhh0[g * 512 + u];
  } else if (i < R1) {
    int j = (int)(i - R0);
    int u = j >> 2, g = j & 3;
    bg1c[j] = bih1[g * 512 + u] + bhh1[g * 512 + u];
  } else if (i < R2) {
    czero[i - R1] = 0.f;
  } else if (i < R3) {
    hzero[i - R2] = 0u;
  } else if (i < R4) {
    long long j = i - R3;
    int c = j & 7;
    long long t = j >> 3;
    int iw = t % 70; t /= 70;
    int ih = t % 70;
    int n = t / 70;
    float v = 0.f;
    if (c < 3 && ih >= 3 && ih < 67 && iw >= 3 && iw < 67)
      v = x[((n * 3 + c) * 64 + (ih - 3)) * 64 + (iw - 3)];
    xpad[j] = f2h(v);
  } else if (i < R5) {
    int j = (int)(i - R4);
    int kg = j % 416, co = j / 416;
    int ci = kg & 7, tap = kg >> 3;
    float v = 0.f;
    if (tap < 49 && ci < 3) {
      int kh = tap / 7, kw = tap % 7;
      v = w1[((co * 3 + ci) * 7 + kh) * 7 + kw];
    }
    w1r[j] = f2h(v);
  } else if (i < R6) {
    int j = (int)(i - R5);
    int r = j >> 9, k = j & 511;
    int u = r >> 2, g = r & 3;
    wih0c[j] = f2h(wih0[(g * 512 + u) * 512 + k]);
  } else if (i < R7) {
    int j = (int)(i - R6);
    fw1h[j] = f2h(fw1[j]);
  } else if (i < R8) {
    int j = (int)(i - R7);
    int r = j >> 9, k = j & 511;
    int u = r >> 2, g = r & 3;
    wcat0h[j] = f2h(whh0[(g * 512 + u) * 512 + k]);
  } else if (i < R9) {
    int j = (int)(i - R8);
    int r = j >> 10, k = j & 1023;
    int u = r >> 2, g = r & 3;
    int row = g * 512 + u;
    wcat1h[j] = f2h(k < 512 ? wih1[row * 512 + k] : whh1[row * 512 + (k - 512)]);
  }
}

// ---------------- LDS-bounce weight transpose (coalesced both ways) ----------------
__global__ __launch_bounds__(256) void prep_wT(
    const float* __restrict__ w2, const float* __restrict__ w3,
    const float* __restrict__ w4, const float* __restrict__ w5,
    half_t* __restrict__ w2r, half_t* __restrict__ w3r,
    half_t* __restrict__ w4r, half_t* __restrict__ w5r) {
  __shared__ float T[12800];
  int bid = blockIdx.x, tid = threadIdx.x;
  const float* W;
  half_t* D;
  int co, Cin, TAP, lg2;
  if (bid < 128) {
    W = w2; D = w2r; co = bid; Cin = 64; TAP = 49; lg2 = 6;
  } else if (bid < 384) {
    W = w3; D = w3r; co = bid - 128; Cin = 128; TAP = 25; lg2 = 7;
  } else if (bid < 896) {
    W = w4; D = w4r; co = bid - 384; Cin = 256; TAP = 25; lg2 = 8;
  } else {
    W = w5; D = w5r; co = bid - 896; Cin = 512; TAP = 25; lg2 = 9;
  }
  int n = Cin * TAP;
  const float* src = W + (size_t)co * n;
  for (int i = tid; i < n; i += 256) T[i] = src[i];
  __syncthreads();
  half_t* dst = D + (size_t)co * n;
  for (int j = tid; j < n; j += 256) {
    int ci = j & (Cin - 1);
    int tap = j >> lg2;
    dst[j] = f2h(T[ci * TAP + tap]);
  }
}

// ---------------- 64x64 fp16 MFMA conv / GEMM ----------------
// OUTMODE: 0 fp16+bias+leaky; 2 f32 raw partial at z*zstride.
template <int KW, int S, int LOG2CIN, int OUTMODE>
__global__ __launch_bounds__(256) void conv_mfma(
    const half_t* __restrict__ xin, const half_t* __restrict__ wr,
    const float* __restrict__ bias, void* __restrict__ outp,
    int Hin, int Win, int Hout, int Wout, int Cout, int K, int ktiles, float slope,
    long long zstride) {
  constexpr int CIN = 1 << LOG2CIN;
  __shared__ half_t lds[4][4096];
  const int tid = threadIdx.x;
  const int lane = tid & 63, wid = tid >> 6;
  const int sRow = tid >> 2, sCh = tid & 3;
  const int sSwz = sCh ^ ((sRow ^ (sRow >> 2)) & 3);
  const int kt0 = blockIdx.z * ktiles;
  const half_t* gArow = wr + (size_t)(blockIdx.y * 64 + sRow) * K + sSwz * 8;
  int p = blockIdx.x * 64 + sRow;
  int hw = Hout * Wout;
  int n = p / hw;
  int rem = p - n * hw;
  int oh = rem / Wout;
  int ow = rem - oh * Wout;
  const half_t* xb = xin + ((size_t)(n * Hin + oh * S) * Win + ow * S) * CIN;
  const int fr = lane & 15, fc = lane >> 4;
  const int r0 = (wid & 1) * 32, c0 = (wid >> 1) * 32;
  const int sw = (fc ^ ((fr ^ (fr >> 2)) & 3)) * 8;
  const int ia0 = (r0 + fr) * 32 + sw;
  const int ia1 = (r0 + 16 + fr) * 32 + sw;
  const int ib0 = 2048 + (c0 + fr) * 32 + sw;
  const int ib1 = 2048 + (c0 + 16 + fr) * 32 + sw;

  auto stage = [&](int t, int buf) {
    GLD(gArow + (size_t)(kt0 + t) * 32, &lds[buf][wid * 512]);
    int kg = (kt0 + t) * 32 + sSwz * 8;
    int ci = kg & (CIN - 1);
    int tap = kg >> LOG2CIN;
    int kh = tap / KW, kw = tap - kh * KW;
    GLD(xb + (kh * Win + kw) * CIN + ci, &lds[buf][2048 + wid * 512]);
  };

  f32x4 acc00 = {0.f, 0.f, 0.f, 0.f};
  f32x4 acc01 = acc00, acc10 = acc00, acc11 = acc00;

  auto compute = [&](int buf) {
    const half_t* L = &lds[buf][0];
    f16x8 a0 = *(const f16x8*)&L[ia0];
    f16x8 a1 = *(const f16x8*)&L[ia1];
    f16x8 b0 = *(const f16x8*)&L[ib0];
    f16x8 b1 = *(const f16x8*)&L[ib1];
    acc00 = __builtin_amdgcn_mfma_f32_16x16x32_f16(a0, b0, acc00, 0, 0, 0);
    acc01 = __builtin_amdgcn_mfma_f32_16x16x32_f16(a0, b1, acc01, 0, 0, 0);
    acc10 = __builtin_amdgcn_mfma_f32_16x16x32_f16(a1, b0, acc10, 0, 0, 0);
    acc11 = __builtin_amdgcn_mfma_f32_16x16x32_f16(a1, b1, acc11, 0, 0, 0);
  };

  stage(0, 0);
  stage(1, 1);
  stage(2, 2);
  int t = 0;
  for (; t < ktiles - 3; ++t) {
    PHASE_WAIT(4);
    stage(t + 3, (t + 3) & 3);
    compute(t & 3);
  }
  PHASE_WAIT(4);
  compute(t & 3);
  ++t;
  PHASE_WAIT(2);
  compute(t & 3);
  ++t;
  PHASE_WAIT(0);
  compute(t & 3);

#pragma unroll
  for (int am = 0; am < 2; ++am) {
#pragma unroll
    for (int bn = 0; bn < 2; ++bn) {
      f32x4 a = am == 0 ? (bn == 0 ? acc00 : acc01) : (bn == 0 ? acc10 : acc11);
      int co = blockIdx.y * 64 + r0 + am * 16 + fc * 4;
      int px = blockIdx.x * 64 + c0 + bn * 16 + fr;
      size_t o = (size_t)px * Cout + co;
      if (OUTMODE == 2) {
        float* pb = (float*)outp + (size_t)blockIdx.z * zstride;
        *(f32x4*)&pb[o] = a;
      } else {
        f32x4 bb = *(const f32x4*)&bias[co];
        f16x4 hv;
#pragma unroll
        for (int j = 0; j < 4; ++j) {
          float tt = a[j] + bb[j];
          hv[j] = f2h(LEAKY(tt, slope));
        }
        *(f16x4*)&((half_t*)outp)[o] = hv;
      }
    }
  }
}

// ---------------- 128x128 fp16 MFMA conv, XCD-swizzled 1D grid ----------------
// OUTMODE: 0 fp16+bias+leaky; 3 fp16 raw partial at bz*zstride.
template <int KW, int S, int LOG2CIN, int OUTMODE>
__global__ __launch_bounds__(256) void conv_mfma128(
    const half_t* __restrict__ xin, const half_t* __restrict__ wr,
    const float* __restrict__ bias, void* __restrict__ outp,
    int Hin, int Win, int Hout, int Wout, int Cout, int K, int ktiles, float slope,
    long long zstride, int Y, int G) {
  constexpr int CIN = 1 << LOG2CIN;
  __shared__ half_t lds[4][8192];
  const int L = blockIdx.x;
  const int bx = L / G;
  const int g = L % G;
  const int by = g % Y;
  const int bz = g / Y;
  const int tid = threadIdx.x;
  const int lane = tid & 63, wid = tid >> 6;
  const int sRow = tid >> 2, sCh = tid & 3;
  const int sSwz = sCh ^ ((sRow ^ (sRow >> 2)) & 3);
  const int kt0 = bz * ktiles;
  const half_t* gA0 = wr + (size_t)(by * 128 + sRow) * K + sSwz * 8;
  const half_t* gA1 = wr + (size_t)(by * 128 + 64 + sRow) * K + sSwz * 8;
  int hw = Hout * Wout;
  int p0 = bx * 128 + sRow;
  int n0 = p0 / hw, r0p = p0 - n0 * hw, oh0 = r0p / Wout, ow0 = r0p - oh0 * Wout;
  const half_t* xb0 = xin + ((size_t)(n0 * Hin + oh0 * S) * Win + ow0 * S) * CIN;
  int p1 = p0 + 64;
  int n1 = p1 / hw, r1p = p1 - n1 * hw, oh1 = r1p / Wout, ow1 = r1p - oh1 * Wout;
  const half_t* xb1 = xin + ((size_t)(n1 * Hin + oh1 * S) * Win + ow1 * S) * CIN;

  const int fr = lane & 15, fc = lane >> 4;
  const int wr_ = wid & 1, wc_ = wid >> 1;
  const int sw = (fc ^ ((fr ^ (fr >> 2)) & 3)) * 8;
  const int iaB = (wr_ * 64 + fr) * 32 + sw;
  const int ibB = 4096 + (wc_ * 64 + fr) * 32 + sw;

  auto stage = [&](int t, int buf) {
    half_t* LB = &lds[buf][0];
    GLD(gA0 + (size_t)(kt0 + t) * 32, LB + wid * 512);
    GLD(gA1 + (size_t)(kt0 + t) * 32, LB + 2048 + wid * 512);
    int kg = (kt0 + t) * 32 + sSwz * 8;
    int ci = kg & (CIN - 1);
    int tap = kg >> LOG2CIN;
    int kh = tap / KW, kw = tap - kh * KW;
    int xoff = (kh * Win + kw) * CIN + ci;
    GLD(xb0 + xoff, LB + 4096 + wid * 512);
    GLD(xb1 + xoff, LB + 6144 + wid * 512);
  };

  f32x4 acc[4][4];
#pragma unroll
  for (int i = 0; i < 4; ++i)
#pragma unroll
    for (int j = 0; j < 4; ++j) acc[i][j] = (f32x4){0.f, 0.f, 0.f, 0.f};

  auto compute = [&](int buf) {
    const half_t* L2 = &lds[buf][0];
    f16x8 a[4], b[4];
#pragma unroll
    for (int fi = 0; fi < 4; ++fi) a[fi] = *(const f16x8*)&L2[iaB + fi * 512];
#pragma unroll
    for (int fj = 0; fj < 4; ++fj) b[fj] = *(const f16x8*)&L2[ibB + fj * 512];
#pragma unroll
    for (int fi = 0; fi < 4; ++fi)
#pragma unroll
      for (int fj = 0; fj < 4; ++fj)
        acc[fi][fj] = __builtin_amdgcn_mfma_f32_16x16x32_f16(a[fi], b[fj], acc[fi][fj], 0, 0, 0);
  };

  stage(0, 0);
  stage(1, 1);
  stage(2, 2);
  int t = 0;
  for (; t < ktiles - 3; ++t) {
    PHASE_WAIT(8);
    stage(t + 3, (t + 3) & 3);
    compute(t & 3);
  }
  PHASE_WAIT(8);
  compute(t & 3);
  ++t;
  PHASE_WAIT(4);
  compute(t & 3);
  ++t;
  PHASE_WAIT(0);
  compute(t & 3);

#pragma unroll
  for (int fi = 0; fi < 4; ++fi) {
#pragma unroll
    for (int fj = 0; fj < 4; ++fj) {
      int co = by * 128 + wr_ * 64 + fi * 16 + fc * 4;
      int px = bx * 128 + wc_ * 64 + fj * 16 + fr;
      size_t o = (size_t)px * Cout + co;
      if (OUTMODE == 3) {
        half_t* pb = (half_t*)outp + (size_t)bz * zstride;
        f16x4 hv;
#pragma unroll
        for (int j = 0; j < 4; ++j) hv[j] = f2h(acc[fi][fj][j]);
        *(f16x4*)&pb[o] = hv;
      } else {
        f32x4 bb = *(const f32x4*)&bias[co];
        f16x4 hv;
#pragma unroll
        for (int j = 0; j < 4; ++j) {
          float tt = acc[fi][fj][j] + bb[j];
          hv[j] = f2h(LEAKY(tt, slope));
        }
        *(f16x4*)&((half_t*)outp)[o] = hv;
      }
    }
  }
}

// reduce K-split f32 partials (conv5)
__global__ void finalize_part(const float* __restrict__ pb, const float* __restrict__ bias,
                              half_t* __restrict__ out, int size, int nz) {
  int i = blockIdx.x * blockDim.x + threadIdx.x;
  if (i >= size) return;
  float s = bias[i & 511];
  for (int z = 0; z < nz; ++z) s += pb[(size_t)z * size + i];
  out[i] = f2h(LEAKY(s, 0.2f));
}

// reduce fp16 K-split partials, vectorized x8
__global__ void finalize_h(const half_t* __restrict__ pb, const float* __restrict__ bias,
                           half_t* __restrict__ out, int size8, int nz, int cmask,
                           long long zstride) {
  int idx = blockIdx.x * blockDim.x + threadIdx.x;
  if (idx >= size8) return;
  long long i = (long long)idx * 8;
  float s[8];
#pragma unroll
  for (int q = 0; q < 8; ++q) s[q] = bias[(int)((i + q) & cmask)];
  for (int z = 0; z < nz; ++z) {
    f16x8 v = *(const f16x8*)&pb[(size_t)z * zstride + i];
#pragma unroll
    for (int q = 0; q < 8; ++q) s[q] += (float)v[q];
  }
  f16x8 o;
#pragma unroll
  for (int q = 0; q < 8; ++q) o[q] = f2h(LEAKY(s[q], 0.2f));
  *(f16x8*)&out[i] = o;
}

// ---------------- LSTM step 1: xw0c = feat@wih0c^T + bg0c, gates -> h0_1, c0 ----
__global__ __launch_bounds__(256) void lstm0_step(
    const half_t* __restrict__ feat, const half_t* __restrict__ wih0c,
    const float* __restrict__ bg0c, float* __restrict__ xw0c,
    float* __restrict__ c0, half_t* __restrict__ h0out) {
  __shared__ half_t lds[4][8192];
  const int tid = threadIdx.x;
  const int lane = tid & 63, wid = tid >> 6;
  const int ybase = blockIdx.y * 64, bbase = blockIdx.x * 64;
  const int rA0 = wid * 16 + (lane >> 3);
  const int rA1 = rA0 + 8;
  const int chS = ((lane & 7) ^ ((lane >> 3) & 7)) * 8;
  const half_t* gA0 = wih0c + (size_t)(ybase + rA0) * 512 + chS;
  const half_t* gA1 = wih0c + (size_t)(ybase + rA1) * 512 + chS;
  const size_t hb0 = (size_t)(bbase + rA0) * 512 + chS;
  const size_t hb1 = (size_t)(bbase + rA1) * 512 + chS;

  auto stage = [&](int t, int buf) {
    GLD(gA0 + t * 64, &lds[buf][wid * 1024]);
    GLD(gA1 + t * 64, &lds[buf][wid * 1024 + 512]);
    GLD(feat + hb0 + t * 64, &lds[buf][4096 + wid * 1024]);
    GLD(feat + hb1 + t * 64, &lds[buf][4096 + wid * 1024 + 512]);
  };

  const int fr = lane & 15, fc = lane >> 4;
  const int wr_ = wid & 1, wc_ = wid >> 1;

  f32x4 acc[2][2];
#pragma unroll
  for (int fi = 0; fi < 2; ++fi)
#pragma unroll
    for (int fj = 0; fj < 2; ++fj) acc[fi][fj] = (f32x4){0.f, 0.f, 0.f, 0.f};

  auto compute = [&](int buf) {
    const half_t* L = &lds[buf][0];
#pragma unroll
    for (int s = 0; s < 2; ++s) {
      f16x8 a[2], b[2];
#pragma unroll
      for (int fi = 0; fi < 2; ++fi) {
        int row = wr_ * 32 + fi * 16 + fr;
        a[fi] = *(const f16x8*)&L[row * 64 + (((s * 4 + fc) ^ (fr & 7)) * 8)];
      }
#pragma unroll
      for (int fj = 0; fj < 2; ++fj) {
        int brow = wc_ * 32 + fj * 16 + fr;
        b[fj] = *(const f16x8*)&L[4096 + brow * 64 + (((s * 4 + fc) ^ (fr & 7)) * 8)];
      }
#pragma unroll
      for (int fi = 0; fi < 2; ++fi)
#pragma unroll
        for (int fj = 0; fj < 2; ++fj)
          acc[fi][fj] = __builtin_amdgcn_mfma_f32_16x16x32_f16(a[fi], b[fj], acc[fi][fj], 0, 0, 0);
    }
  };

  stage(0, 0);
  stage(1, 1);
  stage(2, 2);
  int t = 0;
  for (; t < 5; ++t) {
    PHASE_WAIT(8);
    stage(t + 3, (t + 3) & 3);
    compute(t & 3);
  }
  PHASE_WAIT(8);
  compute(5 & 3);
  PHASE_WAIT(4);
  compute(6 & 3);
  PHASE_WAIT(0);
  compute(7 & 3);

#pragma unroll
  for (int fi = 0; fi < 2; ++fi) {
#pragma unroll
    for (int fj = 0; fj < 2; ++fj) {
      int Rb = ybase + wr_ * 32 + fi * 16 + fc * 4;  // row = u*4+g, gate = j
      int u = Rb >> 2;
      int b = bbase + wc_ * 32 + fj * 16 + fr;
      f32x4 bb = *(const f32x4*)&bg0c[Rb];
      f32x4 pre;
#pragma unroll
      for (int j = 0; j < 4; ++j) pre[j] = acc[fi][fj][j] + bb[j];
      *(f32x4*)&xw0c[(size_t)b * 2048 + Rb] = pre;
      float ig = sig_(pre[0]);
      float gg = tanhf(pre[2]);
      float og = sig_(pre[3]);
      float cn = ig * gg;  // c_prev = 0
      float hn = og * tanhf(cn);
      int ci = b * 512 + u;
      c0[ci] = cn;
      h0out[ci] = f2h(hn);
    }
  }
}

// ---------------- fused LSTM step + optional fc1 plane ----------------
__global__ __launch_bounds__(256) void lstm_fused(
    const half_t* __restrict__ h0in, half_t* __restrict__ h0out,
    const half_t* __restrict__ h1in, half_t* __restrict__ h1out,
    const half_t* __restrict__ wcat0, const half_t* __restrict__ wcat1,
    const float* __restrict__ xw0c, const float* __restrict__ bg1c,
    float* __restrict__ c0, float* __restrict__ c1,
    half_t* __restrict__ ysout, int zl1, int zfc,
    const half_t* __restrict__ fcw, const float* __restrict__ fcb,
    const half_t* __restrict__ fcin, half_t* __restrict__ fcout) {
  const int bzp = blockIdx.z;
  const bool isFC = (bzp == zfc);
  const bool isL1 = (bzp == zl1);
  if (isFC && blockIdx.y >= 8) return;
  const int NT = isL1 ? 16 : 8;
  const half_t* Asrc = isFC ? fcw : (isL1 ? wcat1 : wcat0);
  const int K = NT * 64;

  __shared__ half_t lds[4][8192];
  const int tid = threadIdx.x;
  const int lane = tid & 63, wid = tid >> 6;
  const int ybase = blockIdx.y * 64, bbase = blockIdx.x * 64;
  const int rA0 = wid * 16 + (lane >> 3);
  const int rA1 = rA0 + 8;
  const int chS = ((lane & 7) ^ ((lane >> 3) & 7)) * 8;
  const half_t* gA0 = Asrc + (size_t)(ybase + rA0) * K + chS;
  const half_t* gA1 = Asrc + (size_t)(ybase + rA1) * K + chS;
  const size_t hb0 = (size_t)(bbase + rA0) * 512 + chS;
  const size_t hb1 = (size_t)(bbase + rA1) * 512 + chS;
  const half_t* bsrc0 = isFC ? fcin : h0in;

  auto stage = [&](int t, int buf) {
    GLD(gA0 + t * 64, &lds[buf][wid * 1024]);
    GLD(gA1 + t * 64, &lds[buf][wid * 1024 + 512]);
    const half_t* hs = (isL1 && t >= 8) ? h1in : bsrc0;
    int koff = (isL1 && t >= 8) ? (t - 8) * 64 : t * 64;
    GLD(hs + hb0 + koff, &lds[buf][4096 + wid * 1024]);
    GLD(hs + hb1 + koff, &lds[buf][4096 + wid * 1024 + 512]);
  };

  const int fr = lane & 15, fc = lane >> 4;
  const int wr_ = wid & 1, wc_ = wid >> 1;

  f32x4 acc[2][2];
#pragma unroll
  for (int fi = 0; fi < 2; ++fi)
#pragma unroll
    for (int fj = 0; fj < 2; ++fj) acc[fi][fj] = (f32x4){0.f, 0.f, 0.f, 0.f};

  auto compute = [&](int buf) {
    const half_t* L = &lds[buf][0];
#pragma unroll
    for (int s = 0; s < 2; ++s) {
      f16x8 a[2], b[2];
#pragma unroll
      for (int fi = 0; fi < 2; ++fi) {
        int row = wr_ * 32 + fi * 16 + fr;
        a[fi] = *(const f16x8*)&L[row * 64 + (((s * 4 + fc) ^ (fr & 7)) * 8)];
      }
#pragma unroll
      for (int fj = 0; fj < 2; ++fj) {
        int brow = wc_ * 32 + fj * 16 + fr;
        b[fj] = *(const f16x8*)&L[4096 + brow * 64 + (((s * 4 + fc) ^ (fr & 7)) * 8)];
      }
#pragma unroll
      for (int fi = 0; fi < 2; ++fi)
#pragma unroll
        for (int fj = 0; fj < 2; ++fj)
          acc[fi][fj] = __builtin_amdgcn_mfma_f32_16x16x32_f16(a[fi], b[fj], acc[fi][fj], 0, 0, 0);
    }
  };

  stage(0, 0);
  stage(1, 1);
  stage(2, 2);
  int t = 0;
  for (; t < NT - 3; ++t) {
    PHASE_WAIT(8);
    stage(t + 3, (t + 3) & 3);
    compute(t & 3);
  }
  PHASE_WAIT(8);
  compute(t & 3);
  ++t;
  PHASE_WAIT(4);
  compute(t & 3);
  ++t;
  PHASE_WAIT(0);
  compute(t & 3);

  if (isFC) {
#pragma unroll
    for (int fi = 0; fi < 2; ++fi) {
#pragma unroll
      for (int fj = 0; fj < 2; ++fj) {
        int Rb = ybase + wr_ * 32 + fi * 16 + fc * 4;  // co base
        int b = bbase + wc_ * 32 + fj * 16 + fr;       // chunk-local row
        f32x4 bb = *(const f32x4*)&fcb[Rb];
        f16x4 hv;
#pragma unroll
        for (int j = 0; j < 4; ++j) {
          float tt = acc[fi][fj][j] + bb[j];
          hv[j] = f2h(LEAKY(tt, 0.01f));
        }
        *(f16x4*)&fcout[(size_t)b * 512 + Rb] = hv;
      }
    }
    return;
  }

  float* c = isL1 ? c1 : c0;
  half_t* hout = isL1 ? h1out : h0out;
#pragma unroll
  for (int fi = 0; fi < 2; ++fi) {
#pragma unroll
    for (int fj = 0; fj < 2; ++fj) {
      int Rb = ybase + wr_ * 32 + fi * 16 + fc * 4;  // row = u*4+g, gate = j
      int u = Rb >> 2;
      int b = bbase + wc_ * 32 + fj * 16 + fr;
      f32x4 bb = isL1 ? *(const f32x4*)&bg1c[Rb]
                      : *(const f32x4*)&xw0c[(size_t)b * 2048 + Rb];
      float p[4];
#pragma unroll
      for (int j = 0; j < 4; ++j) p[j] = acc[fi][fj][j] + bb[j];
      int ci = b * 512 + u;
      float cprev = c[ci];
      float ig = sig_(p[0]);
      float fg = sig_(p[1]);
      float gg = tanhf(p[2]);
      float og = sig_(p[3]);
      float cn = fg * cprev + ig * gg;
      float hn = og * tanhf(cn);
      c[ci] = cn;
      hout[ci] = f2h(hn);
      if (isL1) ysout[ci] = f2h(hn);
    }
  }
}

// ---------------- final FC: sigmoid(fc1o @ fw2.T + fb2), [2560,13] ----------------
__global__ void fc2_sigmoid(const half_t* __restrict__ in, const float* __restrict__ w,
                            const float* __restrict__ b, float* __restrict__ out) {
  int idx = blockIdx.x * blockDim.x + threadIdx.x;
  if (idx >= 2560 * 13) return;
  int j = idx % 13, r = idx / 13;
  const half_t* ip = in + (size_t)r * 512;
  const float* wp = w + j * 512;
  float s = b[j];
  for (int k = 0; k < 512; k += 8) {
    f16x8 hv = *(const f16x8*)&ip[k];
#pragma unroll
    for (int q = 0; q < 8; ++q) s = fmaf((float)hv[q], wp[k + q], s);
  }
  out[idx] = sig_(s);
}

// ---------------- launch ----------------
extern "C" void kernel_launch(void* const* d_in, const int* in_sizes, int n_in,
                              void* d_out, int out_size, void* d_ws, size_t ws_size,
                              hipStream_t stream) {
  const float* x   = (const float*)d_in[0];
  const float* w1  = (const float*)d_in[1];  const float* b1 = (const float*)d_in[2];
  const float* w2  = (const float*)d_in[3];  const float* b2 = (const float*)d_in[4];
  const float* w3  = (const float*)d_in[5];  const float* b3 = (const float*)d_in[6];
  const float* w4  = (const float*)d_in[7];  const float* b4 = (const float*)d_in[8];
  const float* w5  = (const float*)d_in[9];  const float* b5 = (const float*)d_in[10];
  const float* wih0 = (const float*)d_in[11]; const float* whh0 = (const float*)d_in[12];
  const float* bih0 = (const float*)d_in[13]; const float* bhh0 = (const float*)d_in[14];
  const float* wih1 = (const float*)d_in[15]; const float* whh1 = (const float*)d_in[16];
  const float* bih1 = (const float*)d_in[17]; const float* bhh1 = (const float*)d_in[18];
  const float* fw1 = (const float*)d_in[19]; const float* fb1 = (const float*)d_in[20];
  const float* fw2 = (const float*)d_in[21]; const float* fb2 = (const float*)d_in[22];
  float* out = (float*)d_out;

  // ---- workspace layout (within 75.6 MB proven; pb max = conv4 z=5 -> 16.4 MB) ----
  float* bg0c = (float*)d_ws;               // 2048
  float* bg1c = bg0c + 2048;                // 2048
  float* xw0c = bg1c + 2048;                // 262144
  float* c0  = xw0c + 262144;               // 65536
  float* c1  = c0 + 65536;                  // 65536
  half_t* h0a = (half_t*)(c1 + 65536);      // 4 x 65536 halves
  half_t* h0b = h0a + 65536;
  half_t* h1a = h0b + 65536;
  half_t* h1b = h1a + 65536;
  half_t* BUF1 = h1b + 65536;               // 8,388,608  [A1 -> A3 -> feat]
  half_t* BUF2 = BUF1 + 8388608;            // 2,768,896  [A2 -> A4 -> ys+fc1o]
  half_t* w1r  = BUF2 + 2768896;            // 26,624
  half_t* w2r  = w1r + 26624;               // 401,408
  half_t* w3r  = w2r + 401408;              // 819,200
  half_t* w4r  = w3r + 819200;              // 3,276,800
  half_t* w5r  = w4r + 3276800;             // 6,553,600
  half_t* wih0ch = w5r + 6553600;           // 1,048,576
  half_t* wcat0h = wih0ch + 1048576;        // 1,048,576
  half_t* wcat1h = wcat0h + 1048576;        // 2,097,152
  half_t* fw1h   = wcat1h + 2097152;        // 262,144
  half_t* xpad   = fw1h + 262144;           // union: xpad / partial buffers
  half_t* pbH = xpad;
  float* pbC = (float*)xpad;

  half_t* A1 = BUF1;                        // [131072 px][64]
  half_t* A2 = BUF2;                        // [21632][128]
  half_t* A3 = BUF1;                        // [10368][256]
  half_t* A4 = BUF2;                        // [3200][512]  (A2 dead)
  half_t* feat = BUF1;                      // [128][512]   (A3 dead)
  half_t* ys   = BUF2;                      // [2560][512]  (A4 dead post-conv5)
  half_t* fc1o = BUF2 + 1310720;

  dim3 blk(256);

  // ---- prep: elementwise (no LDS, full occupancy) + LDS-bounce transposes ----
  prep_elem<<<38152, blk, 0, stream>>>(
      x, w1, wih0, whh0, bih0, bhh0, wih1, whh1, bih1, bhh1, fw1,
      bg0c, bg1c, c0, (unsigned*)h0a, xpad, w1r, wih0ch, fw1h, wcat0h, wcat1h);
  prep_wT<<<1408, blk, 0, stream>>>(w2, w3, w4, w5, w2r, w3r, w4r, w5r);

  // ---- conv stack ----
  conv_mfma<7, 2, 3, 0><<<dim3(2048, 1, 1), blk, 0, stream>>>(
      xpad, w1r, b1, A1, 70, 70, 32, 32, 64, 416, 13, 0.2f, 0);
  conv_mfma128<7, 2, 6, 3><<<338, blk, 0, stream>>>(
      A1, w2r, b2, pbH, 32, 32, 13, 13, 128, 3136, 49, 0.2f, 2768896LL, 1, 2);
  finalize_h<<<1352, blk, 0, stream>>>(pbH, b2, A2, 346112, 2, 127, 2768896LL);
  conv_mfma128<5, 1, 7, 3><<<324, blk, 0, stream>>>(
      A2, w3r, b3, pbH, 13, 13, 9, 9, 256, 3200, 50, 0.2f, 2654208LL, 2, 4);
  finalize_h<<<1296, blk, 0, stream>>>(pbH, b3, A3, 331776, 2, 255, 2654208LL);
  // conv4: z=5 K-split (ktiles 40), G = Y*Z = 4*5 = 20, 500 blocks (~2 blocks/CU)
  conv_mfma128<5, 1, 8, 3><<<500, blk, 0, stream>>>(
      A3, w4r, b4, pbH, 9, 9, 5, 5, 512, 6400, 40, 0.2f, 1638400LL, 4, 20);
  finalize_h<<<800, blk, 0, stream>>>(pbH, b4, A4, 204800, 5, 511, 1638400LL);
  conv_mfma<5, 1, 9, 2><<<dim3(2, 8, 25), blk, 0, stream>>>(
      A4, w5r, b5, pbC, 5, 5, 1, 1, 512, 12800, 16, 0.2f, 65536LL);
  finalize_part<<<256, blk, 0, stream>>>(pbC, b5, feat, 65536, 25);

  // ---- LSTM step 1 (fused xw0 GEMM + gates) ----
  half_t* h0buf[2] = {h0a, h0b};
  half_t* h1buf[2] = {h1a, h1b};
  lstm0_step<<<dim3(2, 32), blk, 0, stream>>>(feat, wih0ch, bg0c, xw0c, c0, h0b);

  // ---- LSTM steps 2..20, fused l0(t)||l1(t-1)||fc1(chunk t-3) ----
  lstm_fused<<<dim3(2, 32, 2), blk, 0, stream>>>(
      h0buf[1], h0buf[0], h1buf[0], h1buf[1], wcat0h, wcat1h, xw0c, bg1c, c0, c1,
      ys, 1, -1, fw1h, fb1, nullptr, nullptr);
  for (int t = 3; t <= 20; ++t) {
    lstm_fused<<<dim3(2, 32, 3), blk, 0, stream>>>(
        h0buf[(t - 1) & 1], h0buf[t & 1], h1buf[t & 1], h1buf[(t - 1) & 1],
        wcat0h, wcat1h, xw0c, bg1c, c0, c1, ys + (size_t)(t - 2) * 65536,
        1, 2, fw1h, fb1, ys + (size_t)(t - 3) * 65536, fc1o + (size_t)(t - 3) * 65536);
  }
  lstm_fused<<<dim3(2, 32, 2), blk, 0, stream>>>(
      h0buf[0], h0buf[1], h1buf[1], h1buf[0],
      wcat0h, wcat1h, xw0c, bg1c, c0, c1, ys + (size_t)19 * 65536,
      0, 1, fw1h, fb1, ys + (size_t)18 * 65536, fc1o + (size_t)18 * 65536);

  // ---- FC head tail: fc1 chunk 19, then fc2 ----
  conv_mfma<1, 1, 9, 0><<<dim3(2, 8, 1), blk, 0, stream>>>(
      ys + (size_t)19 * 65536, fw1h, fb1, fc1o + (size_t)19 * 65536,
      1, 1, 1, 1, 512, 512, 16, 0.01f, 0);
  fc2_sigmoid<<<130, blk, 0, stream>>>(fc1o, fw2, fb2, out);
}